// Round 1
// baseline (3171.094 us; speedup 1.0000x reference)
//
#include <hip/hip_runtime.h>

#define NCH   256
#define M_PIX 262144
#define MPAD  266240   // 520*512 ; >= M_PIX + 8*512 worst-case alignment pad
#define LDA   40       // padded LDS leading dim (bf16 elements) for 32-wide k tiles

typedef short bf16x8 __attribute__((ext_vector_type(8)));
typedef float f32x4  __attribute__((ext_vector_type(4)));

__device__ __forceinline__ unsigned short f2bf(float f) {
  union { float f; unsigned u; } v; v.f = f;
  unsigned r = v.u + 0x7FFFu + ((v.u >> 16) & 1u);
  return (unsigned short)(r >> 16);
}
__device__ __forceinline__ float bf2f(unsigned short h) {
  union { unsigned u; float f; } v; v.u = ((unsigned)h) << 16;
  return v.f;
}

// ---------------- histogram: per-2048-pixel-block label counts, both segs ----
__global__ __launch_bounds__(256) void k_hist(const int* __restrict__ seg_c,
                                              const int* __restrict__ seg_s,
                                              int* __restrict__ hist) {
  __shared__ int h[16];
  int t = threadIdx.x;
  if (t < 16) h[t] = 0;
  __syncthreads();
  int p0 = blockIdx.x * 2048 + t * 8;
#pragma unroll
  for (int e = 0; e < 8; ++e) {
    atomicAdd(&h[seg_c[p0 + e] & 7], 1);
    atomicAdd(&h[8 + (seg_s[p0 + e] & 7)], 1);
  }
  __syncthreads();
  if (t < 8) hist[blockIdx.x * 8 + t] = h[t];
  else if (t < 16) hist[1024 + blockIdx.x * 8 + (t - 8)] = h[t];
}

// ---------------- scan: totals, 512-aligned offsets, per-block bases, valid --
__global__ __launch_bounds__(256) void k_scan(const int* __restrict__ hist,
                                              int* __restrict__ base,
                                              int* __restrict__ off,
                                              int* __restrict__ cnt,
                                              int* __restrict__ valid) {
  __shared__ int lh[2048];
  __shared__ int tot[16];
  __shared__ int loff[2][9];
  int t = threadIdx.x;
  for (int i = t; i < 2048; i += 256) lh[i] = hist[i];
  __syncthreads();
  if (t < 16) {
    int s = t >> 3, l = t & 7, acc = 0;
    for (int b = 0; b < 128; ++b) acc += lh[s * 1024 + b * 8 + l];
    tot[t] = acc;
  }
  __syncthreads();
  if (t < 2) {
    int run = 0;
    for (int l = 0; l < 8; ++l) {
      loff[t][l] = run;
      run = (run + tot[t * 8 + l] + 511) & ~511;
    }
    loff[t][8] = run;
    for (int l = 0; l < 9; ++l) off[t * 9 + l] = loff[t][l];
    for (int l = 0; l < 8; ++l) cnt[t * 8 + l] = tot[t * 8 + l];
  }
  __syncthreads();
  if (t < 8) {
    long nc = tot[t], ns = tot[8 + t];
    valid[t] = (nc > 10 && ns > 10 && nc < 100 * ns && ns < 100 * nc) ? 1 : 0;
  }
  if (t < 16) {
    int s = t >> 3, l = t & 7;
    int run = loff[s][l];
    for (int b = 0; b < 128; ++b) {
      base[s * 1024 + b * 8 + l] = run;
      run += lh[s * 1024 + b * 8 + l];
    }
  }
}

// ---------------- rank: stable per-pixel destination slot (counting sort) ----
__global__ __launch_bounds__(256) void k_rank(const int* __restrict__ seg_c,
                                              const int* __restrict__ seg_s,
                                              const int* __restrict__ base,
                                              int* __restrict__ dst) {
  __shared__ int sc[8 * 272];
  __shared__ int rb[256 * 8];
  __shared__ int bb[8];
  int t = threadIdx.x;
  for (int s = 0; s < 2; ++s) {
    const int* seg = s ? seg_s : seg_c;
    const int* bas = base + s * 1024 + blockIdx.x * 8;
    int* dd = dst + (size_t)s * M_PIX;
    int p0 = blockIdx.x * 2048 + t * 8;
    unsigned pk2 = 0, cpk = 0;
#pragma unroll
    for (int e = 0; e < 8; ++e) {
      int lb = seg[p0 + e] & 7;
      pk2 |= (unsigned)lb << (3 * e);
      cpk += 1u << (4 * lb);
    }
#pragma unroll
    for (int lq = 0; lq < 8; ++lq) sc[lq * 272 + t] = (int)((cpk >> (4 * lq)) & 15u);
    if (t < 8) bb[t] = bas[t];
    __syncthreads();
    for (int d = 1; d < 256; d <<= 1) {
      int v[8];
#pragma unroll
      for (int lq = 0; lq < 8; ++lq)
        v[lq] = sc[lq * 272 + t] + ((t >= d) ? sc[lq * 272 + t - d] : 0);
      __syncthreads();
#pragma unroll
      for (int lq = 0; lq < 8; ++lq) sc[lq * 272 + t] = v[lq];
      __syncthreads();
    }
#pragma unroll
    for (int lq = 0; lq < 8; ++lq)
      rb[t * 8 + lq] = bb[lq] + sc[lq * 272 + t] - (int)((cpk >> (4 * lq)) & 15u);
#pragma unroll
    for (int e = 0; e < 8; ++e) {
      int lb = (int)((pk2 >> (3 * e)) & 7u);
      int dpos = rb[t * 8 + lb]++;
      dd[p0 + e] = dpos;
    }
    __syncthreads();
  }
}

// ---------------- zero the alignment pads of P -------------------------------
__global__ __launch_bounds__(256) void k_padzero(unsigned short* __restrict__ P,
                                                 const int* __restrict__ off,
                                                 const int* __restrict__ cnt) {
  int l = blockIdx.x;
  int c0, c1;
  if (l < 8) { c0 = off[l] + cnt[l]; c1 = off[l + 1]; }
  else       { c0 = off[8];          c1 = MPAD; }
  int w = c1 - c0;
  if (w <= 0) return;
  for (int r = 0; r < 256; ++r)
    for (int cc = threadIdx.x; cc < w; cc += 256)
      P[(size_t)r * MPAD + c0 + cc] = 0;
}

// ---------------- pack: scatter f32 -> packed bf16 (stable order) ------------
__global__ __launch_bounds__(256) void k_pack(const float* __restrict__ feat,
                                              const int* __restrict__ dst,
                                              unsigned short* __restrict__ P) {
  int t = threadIdx.x;
  long p0 = (long)blockIdx.x * 256;
  int d = dst[p0 + t];
  for (int n = 0; n < 256; ++n) {
    float v = feat[(size_t)n * M_PIX + p0 + t];
    P[(size_t)n * MPAD + d] = f2bf(v);
  }
}

// ---------------- per-(label,channel) sums over packed data ------------------
__global__ __launch_bounds__(256) void k_psum(const unsigned short* __restrict__ P,
                                              const int* __restrict__ off,
                                              float* __restrict__ sum) {
  long p0 = (long)blockIdx.x * 512;
  if (p0 >= off[8]) return;
  int l = 0;
  while (l < 7 && p0 >= off[l + 1]) ++l;
  int n = blockIdx.y;
  int t = threadIdx.x;
  unsigned v = *(const unsigned*)&P[(size_t)n * MPAD + p0 + 2 * t];
  float f = bf2f((unsigned short)(v & 0xFFFFu)) + bf2f((unsigned short)(v >> 16));
#pragma unroll
  for (int d = 32; d > 0; d >>= 1) f += __shfl_down(f, d, 64);
  __shared__ float wsum[4];
  if ((t & 63) == 0) wsum[t >> 6] = f;
  __syncthreads();
  if (t == 0) atomicAdd(&sum[l * 256 + n], wsum[0] + wsum[1] + wsum[2] + wsum[3]);
}

// ---------------- Gram: G_l += P_l P_l^T  (bf16 MFMA, lower quadrants) -------
__global__ __launch_bounds__(256) void k_gram(const unsigned short* __restrict__ P,
                                              const int* __restrict__ off,
                                              float* __restrict__ G) {
  int l = blockIdx.y;
  long o0 = off[l], o1 = off[l + 1];
  long k0 = o0 + (long)blockIdx.x * 1024;
  if (k0 >= o1) return;
  long rem = o1 - k0;
  int ks = rem > 1024 ? 1024 : (int)rem;     // always a multiple of 512
  int qi = (blockIdx.z == 0) ? 0 : 1;
  int qj = (blockIdx.z == 2) ? 1 : 0;

  __shared__ unsigned short As[128 * LDA];
  __shared__ unsigned short Bs[128 * LDA];

  int t = threadIdx.x;
  int wave = t >> 6, lane = t & 63;
  int wr = (wave >> 1) * 64, wc = (wave & 1) * 64;

  f32x4 acc[4][4] = {};

  for (int kk = 0; kk < ks; kk += 32) {
#pragma unroll
    for (int it = 0; it < 2; ++it) {
      int slot = t + it * 256;
      int rr = slot >> 2, gg = slot & 3;
      *(uint4*)&As[rr * LDA + gg * 8] =
          *(const uint4*)&P[(size_t)(qi * 128 + rr) * MPAD + (size_t)(k0 + kk) + gg * 8];
      *(uint4*)&Bs[rr * LDA + gg * 8] =
          *(const uint4*)&P[(size_t)(qj * 128 + rr) * MPAD + (size_t)(k0 + kk) + gg * 8];
    }
    __syncthreads();
    bf16x8 bfr[4];
#pragma unroll
    for (int fj = 0; fj < 4; ++fj)
      bfr[fj] = *(const bf16x8*)&Bs[(wc + fj * 16 + (lane & 15)) * LDA + (lane >> 4) * 8];
#pragma unroll
    for (int fi = 0; fi < 4; ++fi) {
      bf16x8 afr = *(const bf16x8*)&As[(wr + fi * 16 + (lane & 15)) * LDA + (lane >> 4) * 8];
#pragma unroll
      for (int fj = 0; fj < 4; ++fj)
        acc[fi][fj] = __builtin_amdgcn_mfma_f32_16x16x32_bf16(afr, bfr[fj], acc[fi][fj], 0, 0, 0);
    }
    __syncthreads();
  }
  float* Gl = G + ((size_t)l << 16);
  int rb = qi * 128 + wr, cb = qj * 128 + wc;
#pragma unroll
  for (int fi = 0; fi < 4; ++fi)
#pragma unroll
    for (int fj = 0; fj < 4; ++fj) {
      int cc = cb + fj * 16 + (lane & 15);
#pragma unroll
      for (int rg = 0; rg < 4; ++rg) {
        int rr = rb + fi * 16 + (lane >> 4) * 4 + rg;
        atomicAdd(&Gl[rr * 256 + cc], acc[fi][fj][rg]);
      }
    }
}

// ---------------- cov = (G - n*mu*mu^T)/(n-1), lower triangle in place -------
__global__ __launch_bounds__(256) void k_cov(float* __restrict__ G,
                                             const float* __restrict__ sum,
                                             const int* __restrict__ cnt,
                                             float* __restrict__ means) {
  int bid = blockIdx.x;                       // side*8 + l
  float* A = G + ((size_t)bid << 16);
  int t = threadIdx.x;
  __shared__ float mu[256];
  float fc = (float)cnt[bid];
  float m = sum[bid * 256 + t] / fmaxf(fc, 1.0f);
  mu[t] = m;
  means[bid * 256 + t] = m;
  __syncthreads();
  float rdiv = 1.0f / fmaxf(fmaxf(fc, 1.0f) - 1.0f, 1.0f);
  float mt = mu[t];
  for (int i = t; i < 256; ++i) {             // lower triangle only (each cell owned by one thread)
    float g = A[i * 256 + t];
    A[i * 256 + t] = (g - fc * mu[i] * mt) * rdiv;
  }
}

// ---------------- Cholesky (rank-1, LDS packed col-major), write L col-major -
__global__ __launch_bounds__(512) void k_chol(float* __restrict__ G) {
  float* A = G + ((size_t)blockIdx.x << 16);
  __shared__ float Lp[32896];                 // col-major packed lower: off(j)=j*256-j(j-1)/2
  __shared__ float colk[256];
  __shared__ float sinv;
  int t = threadIdx.x;
  for (int i = 0; i < 256; ++i)
    for (int j = t; j <= i; j += 512)
      Lp[j * 256 - (j * (j - 1)) / 2 + (i - j)] = A[i * 256 + j];
  __syncthreads();
  for (int k = 0; k < 256; ++k) {
    int cbk = k * 256 - (k * (k - 1)) / 2;
    if (t == 0) {
      float d = sqrtf(Lp[cbk]);
      Lp[cbk] = d; colk[k] = d; sinv = 1.0f / d;
    }
    __syncthreads();
    float inv = sinv;
    int n = 255 - k;
    for (int e = t; e < n; e += 512) {
      float v = Lp[cbk + 1 + e] * inv;
      Lp[cbk + 1 + e] = v;
      colk[k + 1 + e] = v;
    }
    __syncthreads();
    int A0 = cbk + (256 - k);                 // off(k+1)
    int total = 32896 - A0;
    if (total > 0) {
      int per = (total + 511) >> 9;
      int s0 = A0 + t * per;
      int s1 = s0 + per; if (s1 > 32896) s1 = 32896;
      if (s0 < 32896) {
        int j = (int)((513.0f - sqrtf(263169.0f - 8.0f * (float)s0)) * 0.5f);
        if (j < 0) j = 0; if (j > 255) j = 255;
        while (j > 0 && j * 256 - (j * (j - 1)) / 2 > s0) --j;
        while (j < 255 && (j + 1) * 256 - ((j + 1) * j) / 2 <= s0) ++j;
        int cbase = j * 256 - (j * (j - 1)) / 2;
        int i = j + (s0 - cbase);
        float cj = colk[j];
        for (int f = s0; f < s1; ++f) {
          Lp[f] -= colk[i] * cj;
          if (++i == 256) { ++j; i = j; cj = colk[j]; }
        }
      }
    }
    __syncthreads();
  }
  for (int j = 0; j < 256; ++j) {             // write L column-major: A[j*256+i] = L[i][j]
    int n2 = 256 - j, bse = j * 256 - (j * (j - 1)) / 2;
    for (int e = t; e < n2; e += 512) A[j * 256 + j + e] = Lp[bse + e];
  }
}

// ---------------- T = Ls * Lc^{-1} (back-substitution, T lower), b = mus-T*muc
__global__ __launch_bounds__(256) void k_T(const float* __restrict__ G,
                                           const float* __restrict__ means,
                                           const int* __restrict__ valid,
                                           float* __restrict__ T,
                                           unsigned short* __restrict__ Tb,
                                           float* __restrict__ bvec) {
  int l = blockIdx.x, i = threadIdx.x;
  float* Tl = T + ((size_t)l << 16);
  unsigned short* Tbl = Tb + ((size_t)l << 16);
  if (!valid[l]) {
    for (int j = 0; j < 256; ++j) {
      float v = (i == j) ? 1.0f : 0.0f;
      Tl[i * 256 + j] = v;
      Tbl[i * 256 + j] = f2bf(v);
    }
    bvec[l * 256 + i] = 0.0f;
    return;
  }
  const float* Lc = G + ((size_t)l << 16);        // content, col-major L
  const float* Ls = G + ((size_t)(8 + l) << 16);  // style, col-major L
  for (int j = i + 1; j < 256; ++j) Tbl[i * 256 + j] = 0;
  __shared__ float lcol[256];
  for (int j = 255; j >= 0; --j) {
    __syncthreads();
    int k = j + i;
    if (k < 256) lcol[k] = Lc[j * 256 + k];
    float ls = Ls[j * 256 + i];
    __syncthreads();
    if (i >= j) {
      float a0 = 0, a1 = 0, a2 = 0, a3 = 0;
      int kk = j + 1;
      for (; kk + 3 <= i; kk += 4) {
        a0 += Tl[i * 256 + kk]     * lcol[kk];
        a1 += Tl[i * 256 + kk + 1] * lcol[kk + 1];
        a2 += Tl[i * 256 + kk + 2] * lcol[kk + 2];
        a3 += Tl[i * 256 + kk + 3] * lcol[kk + 3];
      }
      for (; kk <= i; ++kk) a0 += Tl[i * 256 + kk] * lcol[kk];
      float tij = (ls - ((a0 + a1) + (a2 + a3))) / lcol[j];
      Tl[i * 256 + j] = tij;
      Tbl[i * 256 + j] = f2bf(tij);
    }
  }
  __syncthreads();
  __shared__ float muc[256];
  muc[i] = means[l * 256 + i];
  __syncthreads();
  float acc = 0;
  for (int j = 0; j <= i; ++j) acc += Tl[i * 256 + j] * muc[j];
  bvec[l * 256 + i] = means[(8 + l) * 256 + i] - acc;
}

// ---------------- out = T_l * x + b_l on packed pixels (in place in P) -------
__global__ __launch_bounds__(256) void k_outgemm(unsigned short* __restrict__ P,
                                                 const unsigned short* __restrict__ Tb,
                                                 const float* __restrict__ bvec,
                                                 const int* __restrict__ off) {
  long px0 = (long)blockIdx.x * 128;
  if (px0 >= off[8]) return;
  int l = 0;
  while (l < 7 && px0 >= off[l + 1]) ++l;
  const unsigned short* Tl = Tb + ((size_t)l << 16);

  __shared__ unsigned short As[256 * LDA];
  __shared__ unsigned short Bs[128 * LDA];
  __shared__ float bsh[256];

  int t = threadIdx.x, wave = t >> 6, lane = t & 63;
  int wrow = wave * 64;
  bsh[t] = bvec[l * 256 + t];

  f32x4 acc[4][8] = {};

  for (int kk = 0; kk < 256; kk += 32) {
#pragma unroll
    for (int it = 0; it < 4; ++it) {            // A: 256 rows x 32 k
      int slot = t + it * 256;
      int rr = slot >> 2, gg = slot & 3;
      *(uint4*)&As[rr * LDA + gg * 8] = *(const uint4*)&Tl[rr * 256 + kk + gg * 8];
    }
#pragma unroll
    for (int it = 0; it < 2; ++it) {            // B: transpose-stage 32k x 128px
      int slot = t + it * 256;
      int pg = slot & 15, kr = slot >> 4;
      uint4 v = *(const uint4*)&P[(size_t)(kk + kr) * MPAD + px0 + pg * 8];
      const unsigned short* vs = (const unsigned short*)&v;
      int krs = kr ^ ((pg & 3) << 3);           // k-block XOR swizzle (bank spread)
#pragma unroll
      for (int e = 0; e < 8; ++e) Bs[(pg * 8 + e) * LDA + krs] = vs[e];
    }
    __syncthreads();
    if (kk < wrow + 64) {                       // T is lower-triangular: skip dead k-tiles
      bf16x8 bfr[8];
#pragma unroll
      for (int fj = 0; fj < 8; ++fj) {
        int px = fj * 16 + (lane & 15);
        int gs = (lane >> 4) ^ ((px >> 3) & 3);
        bfr[fj] = *(const bf16x8*)&Bs[px * LDA + gs * 8];
      }
#pragma unroll
      for (int fi = 0; fi < 4; ++fi) {
        if (wrow + fi * 16 + 15 >= kk) {
          bf16x8 afr = *(const bf16x8*)&As[(wrow + fi * 16 + (lane & 15)) * LDA + (lane >> 4) * 8];
#pragma unroll
          for (int fj = 0; fj < 8; ++fj)
            acc[fi][fj] = __builtin_amdgcn_mfma_f32_16x16x32_bf16(afr, bfr[fj], acc[fi][fj], 0, 0, 0);
        }
      }
    }
    __syncthreads();
  }
#pragma unroll
  for (int fi = 0; fi < 4; ++fi)
#pragma unroll
    for (int fj = 0; fj < 8; ++fj) {
      long p = px0 + fj * 16 + (lane & 15);
#pragma unroll
      for (int rg = 0; rg < 4; ++rg) {
        int rr = wrow + fi * 16 + (lane >> 4) * 4 + rg;
        float v = acc[fi][fj][rg] + bsh[rr];
        P[(size_t)rr * MPAD + p] = f2bf(v);
      }
    }
}

// ---------------- unpack: gather packed bf16 result -> f32 output ------------
__global__ __launch_bounds__(256) void k_unpack(const unsigned short* __restrict__ P,
                                                const int* __restrict__ dst,
                                                float* __restrict__ out) {
  int t = threadIdx.x;
  long p0 = (long)blockIdx.x * 256;
  int d = dst[p0 + t];
  for (int n = 0; n < 256; ++n)
    out[(size_t)n * M_PIX + p0 + t] = bf2f(P[(size_t)n * MPAD + d]);
}

// =============================================================================
extern "C" void kernel_launch(void* const* d_in, const int* in_sizes, int n_in,
                              void* d_out, int out_size, void* d_ws, size_t ws_size,
                              hipStream_t stream) {
  const float* cfeat = (const float*)d_in[0];
  const float* sfeat = (const float*)d_in[1];
  const int* seg_c   = (const int*)d_in[2];
  const int* seg_s   = (const int*)d_in[3];

  char* ws = (char*)d_ws;
  size_t o = 0;
  auto take = [&](size_t b) { size_t r = o; o += (b + 255) & ~(size_t)255; return r; };

  unsigned short* P  = (unsigned short*)(ws + take((size_t)NCH * MPAD * 2));
  size_t zero_b = o;
  float* G           = (float*)(ws + take((size_t)2 * 8 * 65536 * 4));
  float* sum         = (float*)(ws + take((size_t)2 * 8 * 256 * 4));
  int*   hist        = (int*)(ws + take((size_t)2 * 128 * 8 * 4));
  size_t zero_e = o;
  float* T           = (float*)(ws + take((size_t)8 * 65536 * 4));
  unsigned short* Tb = (unsigned short*)(ws + take((size_t)8 * 65536 * 2));
  int*   dst         = (int*)(ws + take((size_t)2 * M_PIX * 4));
  float* means       = (float*)(ws + take((size_t)2 * 8 * 256 * 4));
  float* bvec        = (float*)(ws + take((size_t)8 * 256 * 4));
  int*   base        = (int*)(ws + take((size_t)2 * 128 * 8 * 4));
  int*   off         = (int*)(ws + take((size_t)2 * 9 * 4));
  int*   cnt         = (int*)(ws + take((size_t)2 * 8 * 4));
  int*   valid       = (int*)(ws + take((size_t)8 * 4));
  (void)ws_size; (void)n_in; (void)in_sizes; (void)out_size;

  hipMemsetAsync(ws + zero_b, 0, zero_e - zero_b, stream);

  k_hist<<<dim3(128), dim3(256), 0, stream>>>(seg_c, seg_s, hist);
  k_scan<<<dim3(1), dim3(256), 0, stream>>>(hist, base, off, cnt, valid);
  k_rank<<<dim3(128), dim3(256), 0, stream>>>(seg_c, seg_s, base, dst);

  // style (side 1) first, then content (side 0); P is reused, stream-serial.
  for (int s = 1; s >= 0; --s) {
    const float* feat = s ? sfeat : cfeat;
    k_padzero<<<dim3(9), dim3(256), 0, stream>>>(P, off + s * 9, cnt + s * 8);
    k_pack<<<dim3(1024), dim3(256), 0, stream>>>(feat, dst + (size_t)s * M_PIX, P);
    k_psum<<<dim3(520, 256), dim3(256), 0, stream>>>(P, off + s * 9, sum + (size_t)s * 8 * 256);
    k_gram<<<dim3(260, 8, 3), dim3(256), 0, stream>>>(P, off + s * 9, G + (size_t)s * 8 * 65536);
  }

  k_cov<<<dim3(16), dim3(256), 0, stream>>>(G, sum, cnt, means);
  k_chol<<<dim3(16), dim3(512), 0, stream>>>(G);
  k_T<<<dim3(8), dim3(256), 0, stream>>>(G, means, valid, T, Tb, bvec);
  k_outgemm<<<dim3(2080), dim3(256), 0, stream>>>(P, Tb, bvec, off);
  k_unpack<<<dim3(1024), dim3(256), 0, stream>>>(P, dst, (float*)d_out);
}

// Round 2
// 2257.656 us; speedup vs baseline: 1.4046x; 1.4046x over previous
//
#include <hip/hip_runtime.h>

#define NCH   256
#define M_PIX 262144
#define MPAD  266240   // 520*512 ; >= M_PIX + 8*512 worst-case alignment pad
#define LDA   40       // padded LDS leading dim (bf16 elements) for 32-wide k tiles

typedef short bf16x8 __attribute__((ext_vector_type(8)));
typedef float f32x4  __attribute__((ext_vector_type(4)));

__device__ __forceinline__ unsigned short f2bf(float f) {
  union { float f; unsigned u; } v; v.f = f;
  unsigned r = v.u + 0x7FFFu + ((v.u >> 16) & 1u);
  return (unsigned short)(r >> 16);
}
__device__ __forceinline__ float bf2f(unsigned short h) {
  union { unsigned u; float f; } v; v.u = ((unsigned)h) << 16;
  return v.f;
}

// ---------------- histogram: per-2048-pixel-block label counts, both segs ----
__global__ __launch_bounds__(256) void k_hist(const int* __restrict__ seg_c,
                                              const int* __restrict__ seg_s,
                                              int* __restrict__ hist) {
  __shared__ int h[16];
  int t = threadIdx.x;
  if (t < 16) h[t] = 0;
  __syncthreads();
  int p0 = blockIdx.x * 2048 + t * 8;
#pragma unroll
  for (int e = 0; e < 8; ++e) {
    atomicAdd(&h[seg_c[p0 + e] & 7], 1);
    atomicAdd(&h[8 + (seg_s[p0 + e] & 7)], 1);
  }
  __syncthreads();
  if (t < 8) hist[blockIdx.x * 8 + t] = h[t];
  else if (t < 16) hist[1024 + blockIdx.x * 8 + (t - 8)] = h[t];
}

// ---------------- scan: totals, 512-aligned offsets, per-block bases, valid --
__global__ __launch_bounds__(256) void k_scan(const int* __restrict__ hist,
                                              int* __restrict__ base,
                                              int* __restrict__ off,
                                              int* __restrict__ cnt,
                                              int* __restrict__ valid) {
  __shared__ int lh[2048];
  __shared__ int tot[16];
  __shared__ int loff[2][9];
  int t = threadIdx.x;
  for (int i = t; i < 2048; i += 256) lh[i] = hist[i];
  __syncthreads();
  if (t < 16) {
    int s = t >> 3, l = t & 7, acc = 0;
    for (int b = 0; b < 128; ++b) acc += lh[s * 1024 + b * 8 + l];
    tot[t] = acc;
  }
  __syncthreads();
  if (t < 2) {
    int run = 0;
    for (int l = 0; l < 8; ++l) {
      loff[t][l] = run;
      run = (run + tot[t * 8 + l] + 511) & ~511;
    }
    loff[t][8] = run;
    for (int l = 0; l < 9; ++l) off[t * 9 + l] = loff[t][l];
    for (int l = 0; l < 8; ++l) cnt[t * 8 + l] = tot[t * 8 + l];
  }
  __syncthreads();
  if (t < 8) {
    long nc = tot[t], ns = tot[8 + t];
    valid[t] = (nc > 10 && ns > 10 && nc < 100 * ns && ns < 100 * nc) ? 1 : 0;
  }
  if (t < 16) {
    int s = t >> 3, l = t & 7;
    int run = loff[s][l];
    for (int b = 0; b < 128; ++b) {
      base[s * 1024 + b * 8 + l] = run;
      run += lh[s * 1024 + b * 8 + l];
    }
  }
}

// ---------------- rank: stable per-pixel destination slot (counting sort) ----
__global__ __launch_bounds__(256) void k_rank(const int* __restrict__ seg_c,
                                              const int* __restrict__ seg_s,
                                              const int* __restrict__ base,
                                              int* __restrict__ dst) {
  __shared__ int sc[8 * 272];
  __shared__ int rb[256 * 8];
  __shared__ int bb[8];
  int t = threadIdx.x;
  for (int s = 0; s < 2; ++s) {
    const int* seg = s ? seg_s : seg_c;
    const int* bas = base + s * 1024 + blockIdx.x * 8;
    int* dd = dst + (size_t)s * M_PIX;
    int p0 = blockIdx.x * 2048 + t * 8;
    unsigned pk2 = 0, cpk = 0;
#pragma unroll
    for (int e = 0; e < 8; ++e) {
      int lb = seg[p0 + e] & 7;
      pk2 |= (unsigned)lb << (3 * e);
      cpk += 1u << (4 * lb);
    }
#pragma unroll
    for (int lq = 0; lq < 8; ++lq) sc[lq * 272 + t] = (int)((cpk >> (4 * lq)) & 15u);
    if (t < 8) bb[t] = bas[t];
    __syncthreads();
    for (int d = 1; d < 256; d <<= 1) {
      int v[8];
#pragma unroll
      for (int lq = 0; lq < 8; ++lq)
        v[lq] = sc[lq * 272 + t] + ((t >= d) ? sc[lq * 272 + t - d] : 0);
      __syncthreads();
#pragma unroll
      for (int lq = 0; lq < 8; ++lq) sc[lq * 272 + t] = v[lq];
      __syncthreads();
    }
#pragma unroll
    for (int lq = 0; lq < 8; ++lq)
      rb[t * 8 + lq] = bb[lq] + sc[lq * 272 + t] - (int)((cpk >> (4 * lq)) & 15u);
#pragma unroll
    for (int e = 0; e < 8; ++e) {
      int lb = (int)((pk2 >> (3 * e)) & 7u);
      int dpos = rb[t * 8 + lb]++;
      dd[p0 + e] = dpos;
    }
    __syncthreads();
  }
}

// ---------------- zero the alignment pads of P -------------------------------
__global__ __launch_bounds__(256) void k_padzero(unsigned short* __restrict__ P,
                                                 const int* __restrict__ off,
                                                 const int* __restrict__ cnt) {
  int l = blockIdx.x;
  int c0, c1;
  if (l < 8) { c0 = off[l] + cnt[l]; c1 = off[l + 1]; }
  else       { c0 = off[8];          c1 = MPAD; }
  int w = c1 - c0;
  if (w <= 0) return;
  for (int r = 0; r < 256; ++r)
    for (int cc = threadIdx.x; cc < w; cc += 256)
      P[(size_t)r * MPAD + c0 + cc] = 0;
}

// ---------------- pack: scatter f32 -> packed bf16 (stable order) ------------
__global__ __launch_bounds__(256) void k_pack(const float* __restrict__ feat,
                                              const int* __restrict__ dst,
                                              unsigned short* __restrict__ P) {
  int t = threadIdx.x;
  long p0 = (long)blockIdx.x * 256;
  int d = dst[p0 + t];
  for (int n = 0; n < 256; ++n) {
    float v = feat[(size_t)n * M_PIX + p0 + t];
    P[(size_t)n * MPAD + d] = f2bf(v);
  }
}

// ---------------- per-(label,channel) sums over packed data ------------------
__global__ __launch_bounds__(256) void k_psum(const unsigned short* __restrict__ P,
                                              const int* __restrict__ off,
                                              float* __restrict__ sum) {
  long p0 = (long)blockIdx.x * 512;
  if (p0 >= off[8]) return;
  int l = 0;
  while (l < 7 && p0 >= off[l + 1]) ++l;
  int t = threadIdx.x;
  __shared__ float wsum[4];
#pragma unroll 1
  for (int e = 0; e < 8; ++e) {
    int n = blockIdx.y * 8 + e;
    unsigned v = *(const unsigned*)&P[(size_t)n * MPAD + p0 + 2 * t];
    float f = bf2f((unsigned short)(v & 0xFFFFu)) + bf2f((unsigned short)(v >> 16));
#pragma unroll
    for (int d = 32; d > 0; d >>= 1) f += __shfl_down(f, d, 64);
    if ((t & 63) == 0) wsum[t >> 6] = f;
    __syncthreads();
    if (t == 0) atomicAdd(&sum[l * 256 + n], wsum[0] + wsum[1] + wsum[2] + wsum[3]);
    __syncthreads();
  }
}

// ---------------- Gram: G_l += P_l P_l^T  (bf16 MFMA, lower quadrants) -------
__global__ __launch_bounds__(256) void k_gram(const unsigned short* __restrict__ P,
                                              const int* __restrict__ off,
                                              float* __restrict__ G) {
  int l = blockIdx.y;
  long o0 = off[l], o1 = off[l + 1];
  long k0 = o0 + (long)blockIdx.x * 1024;
  if (k0 >= o1) return;
  long rem = o1 - k0;
  int ks = rem > 1024 ? 1024 : (int)rem;     // always a multiple of 512
  int qi = (blockIdx.z == 0) ? 0 : 1;
  int qj = (blockIdx.z == 2) ? 1 : 0;

  __shared__ unsigned short As[128 * LDA];
  __shared__ unsigned short Bs[128 * LDA];

  int t = threadIdx.x;
  int wave = t >> 6, lane = t & 63;
  int wr = (wave >> 1) * 64, wc = (wave & 1) * 64;

  f32x4 acc[4][4] = {};

  for (int kk = 0; kk < ks; kk += 32) {
#pragma unroll
    for (int it = 0; it < 2; ++it) {
      int slot = t + it * 256;
      int rr = slot >> 2, gg = slot & 3;
      *(uint4*)&As[rr * LDA + gg * 8] =
          *(const uint4*)&P[(size_t)(qi * 128 + rr) * MPAD + (size_t)(k0 + kk) + gg * 8];
      *(uint4*)&Bs[rr * LDA + gg * 8] =
          *(const uint4*)&P[(size_t)(qj * 128 + rr) * MPAD + (size_t)(k0 + kk) + gg * 8];
    }
    __syncthreads();
    bf16x8 bfr[4];
#pragma unroll
    for (int fj = 0; fj < 4; ++fj)
      bfr[fj] = *(const bf16x8*)&Bs[(wc + fj * 16 + (lane & 15)) * LDA + (lane >> 4) * 8];
#pragma unroll
    for (int fi = 0; fi < 4; ++fi) {
      bf16x8 afr = *(const bf16x8*)&As[(wr + fi * 16 + (lane & 15)) * LDA + (lane >> 4) * 8];
#pragma unroll
      for (int fj = 0; fj < 4; ++fj)
        acc[fi][fj] = __builtin_amdgcn_mfma_f32_16x16x32_bf16(afr, bfr[fj], acc[fi][fj], 0, 0, 0);
    }
    __syncthreads();
  }
  float* Gl = G + ((size_t)l << 16);
  int rb = qi * 128 + wr, cb = qj * 128 + wc;
#pragma unroll
  for (int fi = 0; fi < 4; ++fi)
#pragma unroll
    for (int fj = 0; fj < 4; ++fj) {
      int cc = cb + fj * 16 + (lane & 15);
#pragma unroll
      for (int rg = 0; rg < 4; ++rg) {
        int rr = rb + fi * 16 + (lane >> 4) * 4 + rg;
        atomicAdd(&Gl[rr * 256 + cc], acc[fi][fj][rg]);
      }
    }
}

// ---------------- cov = (G - n*mu*mu^T)/(n-1), lower triangle in place -------
__global__ __launch_bounds__(256) void k_cov(float* __restrict__ G,
                                             const float* __restrict__ sum,
                                             const int* __restrict__ cnt,
                                             float* __restrict__ means) {
  int bid = blockIdx.x;                       // side*8 + l
  float* A = G + ((size_t)bid << 16);
  int t = threadIdx.x;
  __shared__ float mu[256];
  float fc = (float)cnt[bid];
  float m = sum[bid * 256 + t] / fmaxf(fc, 1.0f);
  mu[t] = m;
  means[bid * 256 + t] = m;
  __syncthreads();
  float rdiv = 1.0f / fmaxf(fmaxf(fc, 1.0f) - 1.0f, 1.0f);
  float mt = mu[t];
  for (int i = t; i < 256; ++i) {             // lower triangle only
    float g = A[i * 256 + t];
    A[i * 256 + t] = (g - fc * mu[i] * mt) * rdiv;
  }
}

// ---------------- Cholesky (rank-1, LDS packed col-major), write L col-major -
__global__ __launch_bounds__(512) void k_chol(float* __restrict__ G) {
  float* A = G + ((size_t)blockIdx.x << 16);
  __shared__ float Lp[32896];                 // col-major packed lower
  __shared__ float colk[256];
  __shared__ float sinv;
  int t = threadIdx.x;
  for (int i = 0; i < 256; ++i)
    for (int j = t; j <= i; j += 512)
      Lp[j * 256 - (j * (j - 1)) / 2 + (i - j)] = A[i * 256 + j];
  __syncthreads();
  for (int k = 0; k < 256; ++k) {
    int cbk = k * 256 - (k * (k - 1)) / 2;
    if (t == 0) {
      float d = sqrtf(Lp[cbk]);
      Lp[cbk] = d; colk[k] = d; sinv = 1.0f / d;
    }
    __syncthreads();
    float inv = sinv;
    int n = 255 - k;
    for (int e = t; e < n; e += 512) {
      float v = Lp[cbk + 1 + e] * inv;
      Lp[cbk + 1 + e] = v;
      colk[k + 1 + e] = v;
    }
    __syncthreads();
    int A0 = cbk + (256 - k);                 // off(k+1)
    int total = 32896 - A0;
    if (total > 0) {
      int per = (total + 511) >> 9;
      int s0 = A0 + t * per;
      int s1 = s0 + per; if (s1 > 32896) s1 = 32896;
      if (s0 < 32896) {
        int j = (int)((513.0f - sqrtf(263169.0f - 8.0f * (float)s0)) * 0.5f);
        if (j < 0) j = 0; if (j > 255) j = 255;
        while (j > 0 && j * 256 - (j * (j - 1)) / 2 > s0) --j;
        while (j < 255 && (j + 1) * 256 - ((j + 1) * j) / 2 <= s0) ++j;
        int cbase = j * 256 - (j * (j - 1)) / 2;
        int i = j + (s0 - cbase);
        float cj = colk[j];
        for (int f = s0; f < s1; ++f) {
          Lp[f] -= colk[i] * cj;
          if (++i == 256) { ++j; i = j; cj = colk[j]; }
        }
      }
    }
    __syncthreads();
  }
  for (int j = 0; j < 256; ++j) {             // write L column-major: A[j*256+i] = L[i][j]
    int n2 = 256 - j, bse = j * 256 - (j * (j - 1)) / 2;
    for (int e = t; e < n2; e += 512) A[j * 256 + j + e] = Lp[bse + e];
  }
}

// ---------------- T = Ls * Lc^{-1}: blocked right-looking solve --------------
// 512 threads = 2 per row (h = t>>8), registers hold residual R row-half in
// four static 32-float arrays (all static indexing). 32-col panels solved in
// LDS; trailing update is register FMAs against LDS-staged Lc rows.
#define RQ_INIT(q, rq)                                                          \
  _Pragma("unroll") for (int kl = 0; kl < 32; ++kl) {                           \
    int kg = h * 128 + q * 32 + kl;                                             \
    rq[kl] = (i >= kg) ? Ls[(size_t)kg * 256 + i] : 0.0f;                       \
  }

#define RQ_COPY(rq)                                                             \
  _Pragma("unroll") for (int jl = 0; jl < 32; ++jl) Rp[i * 33 + jl] = rq[jl];

#define P2Q(q, rq)                                                              \
  if ((h * 128 + q * 32 + 32) <= jbase) {                                       \
    _Pragma("unroll") for (int kg = 0; kg < 8; ++kg) {                          \
      _Pragma("unroll") for (int jl = 0; jl < 32; ++jl) {                       \
        const float4 lc =                                                       \
            *(const float4*)&LcRows[jl * 260 + h * 128 + q * 32 + kg * 4];      \
        rq[kg * 4 + 0] -= tv[jl] * lc.x;                                        \
        rq[kg * 4 + 1] -= tv[jl] * lc.y;                                        \
        rq[kg * 4 + 2] -= tv[jl] * lc.z;                                        \
        rq[kg * 4 + 3] -= tv[jl] * lc.w;                                        \
      }                                                                         \
    }                                                                           \
  }

__global__ __launch_bounds__(512) void k_T(const float* __restrict__ G,
                                           const float* __restrict__ means,
                                           const int* __restrict__ valid,
                                           unsigned short* __restrict__ Tb,
                                           float* __restrict__ bvec) {
  int l = blockIdx.x;
  int t = threadIdx.x;
  unsigned short* Tbl = Tb + ((size_t)l << 16);
  if (!valid[l]) {
    for (int x = t; x < 65536; x += 512) {
      int rr = x >> 8, cc = x & 255;
      Tbl[x] = f2bf(rr == cc ? 1.0f : 0.0f);
    }
    if (t < 256) bvec[l * 256 + t] = 0.0f;
    return;
  }
  const float* Lc = G + ((size_t)l << 16);        // content L, col-major lower
  const float* Ls = G + ((size_t)(8 + l) << 16);  // style L, col-major lower

  __shared__ float Rp[256 * 33];
  __shared__ float Tp[256 * 33];
  __shared__ float LcRows[32 * 260];
  __shared__ float rdg[32];
  __shared__ float muc[256];

  int i = t & 255, h = t >> 8;

  if (t < 256) muc[t] = means[l * 256 + t];

  float r0[32], r1[32], r2[32], r3[32];
  RQ_INIT(0, r0) RQ_INIT(1, r1) RQ_INIT(2, r2) RQ_INIT(3, r3)
  float bacc = 0.0f;

#pragma unroll 1
  for (int jb = 7; jb >= 0; --jb) {
    int jbase = jb * 32;
    __syncthreads();                              // protect LDS from prev readers
    // stage Lc rows [jbase, jbase+32) x cols [0,256) (zeros above diagonal)
    for (int idx = t; idx < 32 * 256; idx += 512) {
      int c = idx >> 5, jl = idx & 31;
      int j = jbase + jl;
      LcRows[jl * 260 + c] = (c <= j) ? Lc[(size_t)c * 256 + j] : 0.0f;
    }
    if (t < 32) rdg[t] = 1.0f / Lc[(size_t)(jbase + t) * 256 + (jbase + t)];
    // owner half copies its register quarter into the panel residual
    if (h == (jb >> 2)) {
      int q = jb & 3;
      if (q == 0) { RQ_COPY(r0) }
      else if (q == 1) { RQ_COPY(r1) }
      else if (q == 2) { RQ_COPY(r2) }
      else { RQ_COPY(r3) }
    }
    __syncthreads();

    // phase 1: solve 32 columns (descending) inside the panel, in LDS
#pragma unroll 1
    for (int jl = 31; jl >= 0; --jl) {
      float tij = Rp[i * 33 + jl] * rdg[jl];
#pragma unroll
      for (int kl16 = 0; kl16 < 16; ++kl16) {
        int kl = h * 16 + kl16;
        if (kl < jl)
          Rp[i * 33 + kl] -= tij * LcRows[jl * 260 + jbase + kl];
      }
      if (h == 0) Tp[i * 33 + jl] = tij;
      __syncthreads();
    }

    // write bf16 T panel (upper-triangle rows are exactly 0)
#pragma unroll
    for (int e = 0; e < 16; ++e) {
      int jl = h * 16 + e;
      Tbl[(size_t)i * 256 + jbase + jl] = f2bf(Tp[i * 33 + jl]);
    }
    // accumulate b = T * muc contribution (h==0 owns it)
    if (h == 0) {
#pragma unroll
      for (int jl = 0; jl < 32; ++jl) bacc += Tp[i * 33 + jl] * muc[jbase + jl];
    }

    // phase 2: trailing register update  r -= Tpanel * LcRows
    float tv[32];
#pragma unroll
    for (int jl = 0; jl < 32; ++jl) tv[jl] = Tp[i * 33 + jl];
    P2Q(0, r0) P2Q(1, r1) P2Q(2, r2) P2Q(3, r3)
  }

  if (h == 0) bvec[l * 256 + i] = means[(8 + l) * 256 + i] - bacc;
}

// ---------------- out = T_l * x + b_l on packed pixels (in place in P) -------
__global__ __launch_bounds__(256) void k_outgemm(unsigned short* __restrict__ P,
                                                 const unsigned short* __restrict__ Tb,
                                                 const float* __restrict__ bvec,
                                                 const int* __restrict__ off) {
  long px0 = (long)blockIdx.x * 128;
  if (px0 >= off[8]) return;
  int l = 0;
  while (l < 7 && px0 >= off[l + 1]) ++l;
  const unsigned short* Tl = Tb + ((size_t)l << 16);

  __shared__ unsigned short As[256 * LDA];
  __shared__ unsigned short Bs[128 * LDA];
  __shared__ float bsh[256];

  int t = threadIdx.x, wave = t >> 6, lane = t & 63;
  int wrow = wave * 64;
  bsh[t] = bvec[l * 256 + t];

  f32x4 acc[4][8] = {};

  for (int kk = 0; kk < 256; kk += 32) {
#pragma unroll
    for (int it = 0; it < 4; ++it) {            // A: 256 rows x 32 k
      int slot = t + it * 256;
      int rr = slot >> 2, gg = slot & 3;
      *(uint4*)&As[rr * LDA + gg * 8] = *(const uint4*)&Tl[rr * 256 + kk + gg * 8];
    }
#pragma unroll
    for (int it = 0; it < 2; ++it) {            // B: transpose-stage 32k x 128px
      int slot = t + it * 256;
      int pg = slot & 15, kr = slot >> 4;
      uint4 v = *(const uint4*)&P[(size_t)(kk + kr) * MPAD + px0 + pg * 8];
      const unsigned short* vs = (const unsigned short*)&v;
      int krs = kr ^ ((pg & 3) << 3);           // k-block XOR swizzle (bank spread)
#pragma unroll
      for (int e = 0; e < 8; ++e) Bs[(pg * 8 + e) * LDA + krs] = vs[e];
    }
    __syncthreads();
    if (kk < wrow + 64) {                       // T is lower-triangular: skip dead k-tiles
      bf16x8 bfr[8];
#pragma unroll
      for (int fj = 0; fj < 8; ++fj) {
        int px = fj * 16 + (lane & 15);
        int gs = (lane >> 4) ^ ((px >> 3) & 3);
        bfr[fj] = *(const bf16x8*)&Bs[px * LDA + gs * 8];
      }
#pragma unroll
      for (int fi = 0; fi < 4; ++fi) {
        if (wrow + fi * 16 + 15 >= kk) {
          bf16x8 afr = *(const bf16x8*)&As[(wrow + fi * 16 + (lane & 15)) * LDA + (lane >> 4) * 8];
#pragma unroll
          for (int fj = 0; fj < 8; ++fj)
            acc[fi][fj] = __builtin_amdgcn_mfma_f32_16x16x32_bf16(afr, bfr[fj], acc[fi][fj], 0, 0, 0);
        }
      }
    }
    __syncthreads();
  }
#pragma unroll
  for (int fi = 0; fi < 4; ++fi)
#pragma unroll
    for (int fj = 0; fj < 8; ++fj) {
      long p = px0 + fj * 16 + (lane & 15);
#pragma unroll
      for (int rg = 0; rg < 4; ++rg) {
        int rr = wrow + fi * 16 + (lane >> 4) * 4 + rg;
        float v = acc[fi][fj][rg] + bsh[rr];
        P[(size_t)rr * MPAD + p] = f2bf(v);
      }
    }
}

// ---------------- unpack: gather packed bf16 result -> f32 output ------------
__global__ __launch_bounds__(256) void k_unpack(const unsigned short* __restrict__ P,
                                                const int* __restrict__ dst,
                                                float* __restrict__ out) {
  int t = threadIdx.x;
  long p0 = (long)blockIdx.x * 256;
  int d = dst[p0 + t];
  for (int n = 0; n < 256; ++n)
    out[(size_t)n * M_PIX + p0 + t] = bf2f(P[(size_t)n * MPAD + d]);
}

// =============================================================================
extern "C" void kernel_launch(void* const* d_in, const int* in_sizes, int n_in,
                              void* d_out, int out_size, void* d_ws, size_t ws_size,
                              hipStream_t stream) {
  const float* cfeat = (const float*)d_in[0];
  const float* sfeat = (const float*)d_in[1];
  const int* seg_c   = (const int*)d_in[2];
  const int* seg_s   = (const int*)d_in[3];

  char* ws = (char*)d_ws;
  size_t o = 0;
  auto take = [&](size_t b) { size_t r = o; o += (b + 255) & ~(size_t)255; return r; };

  unsigned short* P  = (unsigned short*)(ws + take((size_t)NCH * MPAD * 2));
  size_t zero_b = o;
  float* G           = (float*)(ws + take((size_t)2 * 8 * 65536 * 4));
  float* sum         = (float*)(ws + take((size_t)2 * 8 * 256 * 4));
  int*   hist        = (int*)(ws + take((size_t)2 * 128 * 8 * 4));
  size_t zero_e = o;
  unsigned short* Tb = (unsigned short*)(ws + take((size_t)8 * 65536 * 2));
  int*   dst         = (int*)(ws + take((size_t)2 * M_PIX * 4));
  float* means       = (float*)(ws + take((size_t)2 * 8 * 256 * 4));
  float* bvec        = (float*)(ws + take((size_t)8 * 256 * 4));
  int*   base        = (int*)(ws + take((size_t)2 * 128 * 8 * 4));
  int*   off         = (int*)(ws + take((size_t)2 * 9 * 4));
  int*   cnt         = (int*)(ws + take((size_t)2 * 8 * 4));
  int*   valid       = (int*)(ws + take((size_t)8 * 4));
  (void)ws_size; (void)n_in; (void)in_sizes; (void)out_size;

  hipMemsetAsync(ws + zero_b, 0, zero_e - zero_b, stream);

  k_hist<<<dim3(128), dim3(256), 0, stream>>>(seg_c, seg_s, hist);
  k_scan<<<dim3(1), dim3(256), 0, stream>>>(hist, base, off, cnt, valid);
  k_rank<<<dim3(128), dim3(256), 0, stream>>>(seg_c, seg_s, base, dst);

  // style (side 1) first, then content (side 0); P is reused, stream-serial.
  for (int s = 1; s >= 0; --s) {
    const float* feat = s ? sfeat : cfeat;
    k_padzero<<<dim3(9), dim3(256), 0, stream>>>(P, off + s * 9, cnt + s * 8);
    k_pack<<<dim3(1024), dim3(256), 0, stream>>>(feat, dst + (size_t)s * M_PIX, P);
    k_psum<<<dim3(520, 32), dim3(256), 0, stream>>>(P, off + s * 9, sum + (size_t)s * 8 * 256);
    k_gram<<<dim3(260, 8, 3), dim3(256), 0, stream>>>(P, off + s * 9, G + (size_t)s * 8 * 65536);
  }

  k_cov<<<dim3(16), dim3(256), 0, stream>>>(G, sum, cnt, means);
  k_chol<<<dim3(16), dim3(512), 0, stream>>>(G);
  k_T<<<dim3(8), dim3(512), 0, stream>>>(G, means, valid, Tb, bvec);
  k_outgemm<<<dim3(2080), dim3(256), 0, stream>>>(P, Tb, bvec, off);
  k_unpack<<<dim3(1024), dim3(256), 0, stream>>>(P, dst, (float*)d_out);
}

// Round 3
// 1926.199 us; speedup vs baseline: 1.6463x; 1.1721x over previous
//
#include <hip/hip_runtime.h>

#define NCH   256
#define M_PIX 262144
#define MPAD  266240   // 520*512 ; >= M_PIX + 8*512 worst-case alignment pad
#define LDA   40       // padded LDS leading dim (bf16 elements) for 32-wide k tiles

typedef short bf16x8 __attribute__((ext_vector_type(8)));
typedef float f32x4  __attribute__((ext_vector_type(4)));

__device__ __forceinline__ unsigned short f2bf(float f) {
  union { float f; unsigned u; } v; v.f = f;
  unsigned r = v.u + 0x7FFFu + ((v.u >> 16) & 1u);
  return (unsigned short)(r >> 16);
}
__device__ __forceinline__ float bf2f(unsigned short h) {
  union { unsigned u; float f; } v; v.u = ((unsigned)h) << 16;
  return v.f;
}
__device__ __forceinline__ int packoff(int j) { return j * 256 - ((j * (j - 1)) >> 1); }

// ---------------- histogram: per-2048-pixel-block label counts, both segs ----
__global__ __launch_bounds__(256) void k_hist(const int* __restrict__ seg_c,
                                              const int* __restrict__ seg_s,
                                              int* __restrict__ hist) {
  __shared__ int h[16];
  int t = threadIdx.x;
  if (t < 16) h[t] = 0;
  __syncthreads();
  int p0 = blockIdx.x * 2048 + t * 8;
#pragma unroll
  for (int e = 0; e < 8; ++e) {
    atomicAdd(&h[seg_c[p0 + e] & 7], 1);
    atomicAdd(&h[8 + (seg_s[p0 + e] & 7)], 1);
  }
  __syncthreads();
  if (t < 8) hist[blockIdx.x * 8 + t] = h[t];
  else if (t < 16) hist[1024 + blockIdx.x * 8 + (t - 8)] = h[t];
}

// ---------------- scan: totals, 512-aligned offsets, per-block bases, valid --
__global__ __launch_bounds__(256) void k_scan(const int* __restrict__ hist,
                                              int* __restrict__ base,
                                              int* __restrict__ off,
                                              int* __restrict__ cnt,
                                              int* __restrict__ valid) {
  __shared__ int lh[2048];
  __shared__ int tot[16];
  __shared__ int loff[2][9];
  int t = threadIdx.x;
  for (int i = t; i < 2048; i += 256) lh[i] = hist[i];
  __syncthreads();
  if (t < 16) {
    int s = t >> 3, l = t & 7, acc = 0;
    for (int b = 0; b < 128; ++b) acc += lh[s * 1024 + b * 8 + l];
    tot[t] = acc;
  }
  __syncthreads();
  if (t < 2) {
    int run = 0;
    for (int l = 0; l < 8; ++l) {
      loff[t][l] = run;
      run = (run + tot[t * 8 + l] + 511) & ~511;
    }
    loff[t][8] = run;
    for (int l = 0; l < 9; ++l) off[t * 9 + l] = loff[t][l];
    for (int l = 0; l < 8; ++l) cnt[t * 8 + l] = tot[t * 8 + l];
  }
  __syncthreads();
  if (t < 8) {
    long nc = tot[t], ns = tot[8 + t];
    valid[t] = (nc > 10 && ns > 10 && nc < 100 * ns && ns < 100 * nc) ? 1 : 0;
  }
  if (t < 16) {
    int s = t >> 3, l = t & 7;
    int run = loff[s][l];
    for (int b = 0; b < 128; ++b) {
      base[s * 1024 + b * 8 + l] = run;
      run += lh[s * 1024 + b * 8 + l];
    }
  }
}

// ---------------- rank: stable per-pixel destination slot (counting sort) ----
__global__ __launch_bounds__(256) void k_rank(const int* __restrict__ seg_c,
                                              const int* __restrict__ seg_s,
                                              const int* __restrict__ base,
                                              int* __restrict__ dst) {
  __shared__ int sc[8 * 272];
  __shared__ int rb[256 * 8];
  __shared__ int bb[8];
  int t = threadIdx.x;
  for (int s = 0; s < 2; ++s) {
    const int* seg = s ? seg_s : seg_c;
    const int* bas = base + s * 1024 + blockIdx.x * 8;
    int* dd = dst + (size_t)s * M_PIX;
    int p0 = blockIdx.x * 2048 + t * 8;
    unsigned pk2 = 0, cpk = 0;
#pragma unroll
    for (int e = 0; e < 8; ++e) {
      int lb = seg[p0 + e] & 7;
      pk2 |= (unsigned)lb << (3 * e);
      cpk += 1u << (4 * lb);
    }
#pragma unroll
    for (int lq = 0; lq < 8; ++lq) sc[lq * 272 + t] = (int)((cpk >> (4 * lq)) & 15u);
    if (t < 8) bb[t] = bas[t];
    __syncthreads();
    for (int d = 1; d < 256; d <<= 1) {
      int v[8];
#pragma unroll
      for (int lq = 0; lq < 8; ++lq)
        v[lq] = sc[lq * 272 + t] + ((t >= d) ? sc[lq * 272 + t - d] : 0);
      __syncthreads();
#pragma unroll
      for (int lq = 0; lq < 8; ++lq) sc[lq * 272 + t] = v[lq];
      __syncthreads();
    }
#pragma unroll
    for (int lq = 0; lq < 8; ++lq)
      rb[t * 8 + lq] = bb[lq] + sc[lq * 272 + t] - (int)((cpk >> (4 * lq)) & 15u);
#pragma unroll
    for (int e = 0; e < 8; ++e) {
      int lb = (int)((pk2 >> (3 * e)) & 7u);
      int dpos = rb[t * 8 + lb]++;
      dd[p0 + e] = dpos;
    }
    __syncthreads();
  }
}

// ---------------- zero the alignment pads of P -------------------------------
__global__ __launch_bounds__(256) void k_padzero(unsigned short* __restrict__ P,
                                                 const int* __restrict__ off,
                                                 const int* __restrict__ cnt) {
  int l = blockIdx.x;
  int c0, c1;
  if (l < 8) { c0 = off[l] + cnt[l]; c1 = off[l + 1]; }
  else       { c0 = off[8];          c1 = MPAD; }
  int w = c1 - c0;
  if (w <= 0) return;
  for (int r = 0; r < 256; ++r)
    for (int cc = threadIdx.x; cc < w; cc += 256)
      P[(size_t)r * MPAD + c0 + cc] = 0;
}

// ---------------- pack: scatter f32 -> packed bf16 (stable order) ------------
__global__ __launch_bounds__(256) void k_pack(const float* __restrict__ feat,
                                              const int* __restrict__ dst,
                                              unsigned short* __restrict__ P) {
  int t = threadIdx.x;
  long p0 = (long)blockIdx.x * 256;
  int d = dst[p0 + t];
  for (int n = 0; n < 256; ++n) {
    float v = feat[(size_t)n * M_PIX + p0 + t];
    P[(size_t)n * MPAD + d] = f2bf(v);
  }
}

// ---------------- per-(label,channel) sums over packed data ------------------
__global__ __launch_bounds__(256) void k_psum(const unsigned short* __restrict__ P,
                                              const int* __restrict__ off,
                                              float* __restrict__ sum) {
  long p0 = (long)blockIdx.x * 512;
  if (p0 >= off[8]) return;
  int l = 0;
  while (l < 7 && p0 >= off[l + 1]) ++l;
  int t = threadIdx.x;
  __shared__ float wsum[4];
#pragma unroll 1
  for (int e = 0; e < 8; ++e) {
    int n = blockIdx.y * 8 + e;
    unsigned v = *(const unsigned*)&P[(size_t)n * MPAD + p0 + 2 * t];
    float f = bf2f((unsigned short)(v & 0xFFFFu)) + bf2f((unsigned short)(v >> 16));
#pragma unroll
    for (int d = 32; d > 0; d >>= 1) f += __shfl_down(f, d, 64);
    if ((t & 63) == 0) wsum[t >> 6] = f;
    __syncthreads();
    if (t == 0) atomicAdd(&sum[l * 256 + n], wsum[0] + wsum[1] + wsum[2] + wsum[3]);
    __syncthreads();
  }
}

// ---------------- Gram: G_l += P_l P_l^T  (bf16 MFMA, lower quadrants) -------
__global__ __launch_bounds__(256) void k_gram(const unsigned short* __restrict__ P,
                                              const int* __restrict__ off,
                                              float* __restrict__ G) {
  int l = blockIdx.y;
  long o0 = off[l], o1 = off[l + 1];
  long k0 = o0 + (long)blockIdx.x * 1024;
  if (k0 >= o1) return;
  long rem = o1 - k0;
  int ks = rem > 1024 ? 1024 : (int)rem;     // always a multiple of 512
  int qi = (blockIdx.z == 0) ? 0 : 1;
  int qj = (blockIdx.z == 2) ? 1 : 0;

  __shared__ unsigned short As[128 * LDA];
  __shared__ unsigned short Bs[128 * LDA];

  int t = threadIdx.x;
  int wave = t >> 6, lane = t & 63;
  int wr = (wave >> 1) * 64, wc = (wave & 1) * 64;

  f32x4 acc[4][4] = {};

  for (int kk = 0; kk < ks; kk += 32) {
#pragma unroll
    for (int it = 0; it < 2; ++it) {
      int slot = t + it * 256;
      int rr = slot >> 2, gg = slot & 3;
      *(uint4*)&As[rr * LDA + gg * 8] =
          *(const uint4*)&P[(size_t)(qi * 128 + rr) * MPAD + (size_t)(k0 + kk) + gg * 8];
      *(uint4*)&Bs[rr * LDA + gg * 8] =
          *(const uint4*)&P[(size_t)(qj * 128 + rr) * MPAD + (size_t)(k0 + kk) + gg * 8];
    }
    __syncthreads();
    bf16x8 bfr[4];
#pragma unroll
    for (int fj = 0; fj < 4; ++fj)
      bfr[fj] = *(const bf16x8*)&Bs[(wc + fj * 16 + (lane & 15)) * LDA + (lane >> 4) * 8];
#pragma unroll
    for (int fi = 0; fi < 4; ++fi) {
      bf16x8 afr = *(const bf16x8*)&As[(wr + fi * 16 + (lane & 15)) * LDA + (lane >> 4) * 8];
#pragma unroll
      for (int fj = 0; fj < 4; ++fj)
        acc[fi][fj] = __builtin_amdgcn_mfma_f32_16x16x32_bf16(afr, bfr[fj], acc[fi][fj], 0, 0, 0);
    }
    __syncthreads();
  }
  float* Gl = G + ((size_t)l << 16);
  int rb = qi * 128 + wr, cb = qj * 128 + wc;
#pragma unroll
  for (int fi = 0; fi < 4; ++fi)
#pragma unroll
    for (int fj = 0; fj < 4; ++fj) {
      int cc = cb + fj * 16 + (lane & 15);
#pragma unroll
      for (int rg = 0; rg < 4; ++rg) {
        int rr = rb + fi * 16 + (lane >> 4) * 4 + rg;
        atomicAdd(&Gl[rr * 256 + cc], acc[fi][fj][rg]);
      }
    }
}

// ---------------- cov = (G - n*mu*mu^T)/(n-1), lower triangle in place -------
__global__ __launch_bounds__(256) void k_cov(float* __restrict__ G,
                                             const float* __restrict__ sum,
                                             const int* __restrict__ cnt,
                                             float* __restrict__ means) {
  int bid = blockIdx.x;                       // side*8 + l
  float* A = G + ((size_t)bid << 16);
  int t = threadIdx.x;
  __shared__ float mu[256];
  float fc = (float)cnt[bid];
  float m = sum[bid * 256 + t] / fmaxf(fc, 1.0f);
  mu[t] = m;
  means[bid * 256 + t] = m;
  __syncthreads();
  float rdiv = 1.0f / fmaxf(fmaxf(fc, 1.0f) - 1.0f, 1.0f);
  float mt = mu[t];
  for (int i = t; i < 256; ++i) {             // lower triangle only
    float g = A[i * 256 + t];
    A[i * 256 + t] = (g - fc * mu[i] * mt) * rdiv;
  }
}

// ---------------- blocked Cholesky (32-col panels, ~4 barriers/panel) --------
// Packed col-major lower triangle in LDS: element (i,j) at Lp[packoff(j)+i-j].
// Panel pb: (1) wave 0 factors the 32x32 diag block wave-synchronously (no
// barriers needed intra-wave); (2) one thread per trailing row solves L21 via
// fully-unrolled forward substitution (static register indexing); (3) trailing
// update A22 -= L21*L21^T as 4x4 register tiles over flat triangular tile ids.
__global__ __launch_bounds__(512) void k_chol(float* __restrict__ G) {
  float* A = G + ((size_t)blockIdx.x << 16);
  __shared__ float Lp[32896];
  __shared__ float Db[32 * 33];
  __shared__ float rdg[32];
  int t = threadIdx.x;
  int lane = t & 63;

  for (int i = 0; i < 256; ++i)
    for (int j = t; j <= i; j += 512)
      Lp[packoff(j) + (i - j)] = A[i * 256 + j];
  __syncthreads();

#pragma unroll 1
  for (int pb = 0; pb < 8; ++pb) {
    int jbase = pb * 32;
    int H2 = 256 - jbase - 32;               // trailing height

    // ---- stage diag block into Db ----
    for (int idx = t; idx < 1024; idx += 512) {
      int i = idx >> 5, j = idx & 31;
      Db[i * 33 + j] = (i >= j) ? Lp[packoff(jbase + j) + (i - j)] : 0.0f;
    }
    __syncthreads();

    // ---- wave 0: factor 32x32 block, wave-synchronous ----
    if (t < 64) {
      int l32 = lane & 31, h = lane >> 5;
#pragma unroll 1
      for (int j = 0; j < 32; ++j) {
        float djj = Db[j * 33 + j];
        float d = sqrtf(djj);
        float rd = 1.0f / d;
        if (lane == 0) { Db[j * 33 + j] = d; rdg[j] = rd; }
        if (h == 0 && l32 > j) Db[l32 * 33 + j] *= rd;
        float Lij = Db[l32 * 33 + j];
        for (int k = j + 1 + h; k <= l32; k += 2)
          Db[l32 * 33 + k] -= Lij * Db[k * 33 + j];
      }
    }
    __syncthreads();

    // ---- write factored diag block back ----
    for (int idx = t; idx < 1024; idx += 512) {
      int i = idx >> 5, j = idx & 31;
      if (i >= j) Lp[packoff(jbase + j) + (i - j)] = Db[i * 33 + j];
    }

    // ---- L21 solve: one thread per trailing row ----
    if (t < H2) {
      int ig = jbase + 32 + t;
      float xx[32];
#pragma unroll
      for (int j = 0; j < 32; ++j)
        xx[j] = Lp[packoff(jbase + j) + (ig - jbase - j)];
#pragma unroll
      for (int j = 0; j < 32; ++j) {
        float x = xx[j];
#pragma unroll
        for (int k = 0; k < 32; ++k)
          if (k < j) x -= xx[k] * Db[j * 33 + k];
        xx[j] = x * rdg[j];
      }
#pragma unroll
      for (int j = 0; j < 32; ++j)
        Lp[packoff(jbase + j) + (ig - jbase - j)] = xx[j];
    }
    __syncthreads();

    // ---- trailing update: 4x4 register tiles ----
    if (H2 > 0) {
      int cbp[32];
#pragma unroll
      for (int jl = 0; jl < 32; ++jl)
        cbp[jl] = packoff(jbase + jl) - (jbase + jl);
      int nts = H2 >> 2;
      int ntiles = (nts * (nts + 1)) >> 1;
#pragma unroll 1
      for (int tile = t; tile < ntiles; tile += 512) {
        int ti = (int)((sqrtf(8.0f * (float)tile + 1.0f) - 1.0f) * 0.5f);
        while (((ti * (ti + 1)) >> 1) > tile) --ti;
        while ((((ti + 1) * (ti + 2)) >> 1) <= tile) ++ti;
        int tj = tile - ((ti * (ti + 1)) >> 1);
        int i0 = jbase + 32 + ti * 4, j0 = jbase + 32 + tj * 4;
        float acc[4][4] = {};
#pragma unroll
        for (int jl = 0; jl < 32; ++jl) {
          float pi0 = Lp[cbp[jl] + i0];
          float pi1 = Lp[cbp[jl] + i0 + 1];
          float pi2 = Lp[cbp[jl] + i0 + 2];
          float pi3 = Lp[cbp[jl] + i0 + 3];
          float pj0 = Lp[cbp[jl] + j0];
          float pj1 = Lp[cbp[jl] + j0 + 1];
          float pj2 = Lp[cbp[jl] + j0 + 2];
          float pj3 = Lp[cbp[jl] + j0 + 3];
          acc[0][0] += pi0 * pj0; acc[0][1] += pi0 * pj1;
          acc[0][2] += pi0 * pj2; acc[0][3] += pi0 * pj3;
          acc[1][0] += pi1 * pj0; acc[1][1] += pi1 * pj1;
          acc[1][2] += pi1 * pj2; acc[1][3] += pi1 * pj3;
          acc[2][0] += pi2 * pj0; acc[2][1] += pi2 * pj1;
          acc[2][2] += pi2 * pj2; acc[2][3] += pi2 * pj3;
          acc[3][0] += pi3 * pj0; acc[3][1] += pi3 * pj1;
          acc[3][2] += pi3 * pj2; acc[3][3] += pi3 * pj3;
        }
#pragma unroll
        for (int c = 0; c < 4; ++c) {
          int jg = j0 + c;
          int colb = packoff(jg) - jg;
#pragma unroll
          for (int r = 0; r < 4; ++r) {
            int ig2 = i0 + r;
            if (ig2 >= jg) Lp[colb + ig2] -= acc[r][c];
          }
        }
      }
    }
    __syncthreads();
  }

  for (int j = 0; j < 256; ++j) {             // write L column-major: A[j*256+i] = L[i][j]
    int n2 = 256 - j, bse = packoff(j);
    for (int e = t; e < n2; e += 512) A[j * 256 + j + e] = Lp[bse + e];
  }
}

// ---------------- T = Ls * Lc^{-1}: blocked right-looking solve --------------
#define RQ_INIT(q, rq)                                                          \
  _Pragma("unroll") for (int kl = 0; kl < 32; ++kl) {                           \
    int kg = h * 128 + q * 32 + kl;                                             \
    rq[kl] = (i >= kg) ? Ls[(size_t)kg * 256 + i] : 0.0f;                       \
  }

#define RQ_COPY(rq)                                                             \
  _Pragma("unroll") for (int jl = 0; jl < 32; ++jl) Rp[i * 33 + jl] = rq[jl];

#define P2Q(q, rq)                                                              \
  if ((h * 128 + q * 32 + 32) <= jbase) {                                       \
    _Pragma("unroll") for (int kg = 0; kg < 8; ++kg) {                          \
      _Pragma("unroll") for (int jl = 0; jl < 32; ++jl) {                       \
        const float4 lc =                                                       \
            *(const float4*)&LcRows[jl * 260 + h * 128 + q * 32 + kg * 4];      \
        rq[kg * 4 + 0] -= tv[jl] * lc.x;                                        \
        rq[kg * 4 + 1] -= tv[jl] * lc.y;                                        \
        rq[kg * 4 + 2] -= tv[jl] * lc.z;                                        \
        rq[kg * 4 + 3] -= tv[jl] * lc.w;                                        \
      }                                                                         \
    }                                                                           \
  }

__global__ __launch_bounds__(512) void k_T(const float* __restrict__ G,
                                           const float* __restrict__ means,
                                           const int* __restrict__ valid,
                                           unsigned short* __restrict__ Tb,
                                           float* __restrict__ bvec) {
  int l = blockIdx.x;
  int t = threadIdx.x;
  unsigned short* Tbl = Tb + ((size_t)l << 16);
  if (!valid[l]) {
    for (int x = t; x < 65536; x += 512) {
      int rr = x >> 8, cc = x & 255;
      Tbl[x] = f2bf(rr == cc ? 1.0f : 0.0f);
    }
    if (t < 256) bvec[l * 256 + t] = 0.0f;
    return;
  }
  const float* Lc = G + ((size_t)l << 16);        // content L, col-major lower
  const float* Ls = G + ((size_t)(8 + l) << 16);  // style L, col-major lower

  __shared__ float Rp[256 * 33];
  __shared__ float Tp[256 * 33];
  __shared__ float LcRows[32 * 260];
  __shared__ float rdg[32];
  __shared__ float muc[256];

  int i = t & 255, h = t >> 8;

  if (t < 256) muc[t] = means[l * 256 + t];

  float r0[32], r1[32], r2[32], r3[32];
  RQ_INIT(0, r0) RQ_INIT(1, r1) RQ_INIT(2, r2) RQ_INIT(3, r3)
  float bacc = 0.0f;

#pragma unroll 1
  for (int jb = 7; jb >= 0; --jb) {
    int jbase = jb * 32;
    __syncthreads();                              // protect LDS from prev readers
    for (int idx = t; idx < 32 * 256; idx += 512) {
      int c = idx >> 5, jl = idx & 31;
      int j = jbase + jl;
      LcRows[jl * 260 + c] = (c <= j) ? Lc[(size_t)c * 256 + j] : 0.0f;
    }
    if (t < 32) rdg[t] = 1.0f / Lc[(size_t)(jbase + t) * 256 + (jbase + t)];
    if (h == (jb >> 2)) {
      int q = jb & 3;
      if (q == 0) { RQ_COPY(r0) }
      else if (q == 1) { RQ_COPY(r1) }
      else if (q == 2) { RQ_COPY(r2) }
      else { RQ_COPY(r3) }
    }
    __syncthreads();

#pragma unroll 1
    for (int jl = 31; jl >= 0; --jl) {
      float tij = Rp[i * 33 + jl] * rdg[jl];
#pragma unroll
      for (int kl16 = 0; kl16 < 16; ++kl16) {
        int kl = h * 16 + kl16;
        if (kl < jl)
          Rp[i * 33 + kl] -= tij * LcRows[jl * 260 + jbase + kl];
      }
      if (h == 0) Tp[i * 33 + jl] = tij;
      __syncthreads();
    }

#pragma unroll
    for (int e = 0; e < 16; ++e) {
      int jl = h * 16 + e;
      Tbl[(size_t)i * 256 + jbase + jl] = f2bf(Tp[i * 33 + jl]);
    }
    if (h == 0) {
#pragma unroll
      for (int jl = 0; jl < 32; ++jl) bacc += Tp[i * 33 + jl] * muc[jbase + jl];
    }

    float tv[32];
#pragma unroll
    for (int jl = 0; jl < 32; ++jl) tv[jl] = Tp[i * 33 + jl];
    P2Q(0, r0) P2Q(1, r1) P2Q(2, r2) P2Q(3, r3)
  }

  if (h == 0) bvec[l * 256 + i] = means[(8 + l) * 256 + i] - bacc;
}

// ---------------- out = T_l * x + b_l on packed pixels (in place in P) -------
__global__ __launch_bounds__(256) void k_outgemm(unsigned short* __restrict__ P,
                                                 const unsigned short* __restrict__ Tb,
                                                 const float* __restrict__ bvec,
                                                 const int* __restrict__ off) {
  long px0 = (long)blockIdx.x * 128;
  if (px0 >= off[8]) return;
  int l = 0;
  while (l < 7 && px0 >= off[l + 1]) ++l;
  const unsigned short* Tl = Tb + ((size_t)l << 16);

  __shared__ unsigned short As[256 * LDA];
  __shared__ unsigned short Bs[128 * LDA];
  __shared__ float bsh[256];

  int t = threadIdx.x, wave = t >> 6, lane = t & 63;
  int wrow = wave * 64;
  bsh[t] = bvec[l * 256 + t];

  f32x4 acc[4][8] = {};

  for (int kk = 0; kk < 256; kk += 32) {
#pragma unroll
    for (int it = 0; it < 4; ++it) {            // A: 256 rows x 32 k
      int slot = t + it * 256;
      int rr = slot >> 2, gg = slot & 3;
      *(uint4*)&As[rr * LDA + gg * 8] = *(const uint4*)&Tl[rr * 256 + kk + gg * 8];
    }
#pragma unroll
    for (int it = 0; it < 2; ++it) {            // B: transpose-stage 32k x 128px
      int slot = t + it * 256;
      int pg = slot & 15, kr = slot >> 4;
      uint4 v = *(const uint4*)&P[(size_t)(kk + kr) * MPAD + px0 + pg * 8];
      const unsigned short* vs = (const unsigned short*)&v;
      int krs = kr ^ ((pg & 3) << 3);           // k-block XOR swizzle (bank spread)
#pragma unroll
      for (int e = 0; e < 8; ++e) Bs[(pg * 8 + e) * LDA + krs] = vs[e];
    }
    __syncthreads();
    if (kk < wrow + 64) {                       // T is lower-triangular: skip dead k-tiles
      bf16x8 bfr[8];
#pragma unroll
      for (int fj = 0; fj < 8; ++fj) {
        int px = fj * 16 + (lane & 15);
        int gs = (lane >> 4) ^ ((px >> 3) & 3);
        bfr[fj] = *(const bf16x8*)&Bs[px * LDA + gs * 8];
      }
#pragma unroll
      for (int fi = 0; fi < 4; ++fi) {
        if (wrow + fi * 16 + 15 >= kk) {
          bf16x8 afr = *(const bf16x8*)&As[(wrow + fi * 16 + (lane & 15)) * LDA + (lane >> 4) * 8];
#pragma unroll
          for (int fj = 0; fj < 8; ++fj)
            acc[fi][fj] = __builtin_amdgcn_mfma_f32_16x16x32_bf16(afr, bfr[fj], acc[fi][fj], 0, 0, 0);
        }
      }
    }
    __syncthreads();
  }
#pragma unroll
  for (int fi = 0; fi < 4; ++fi)
#pragma unroll
    for (int fj = 0; fj < 8; ++fj) {
      long p = px0 + fj * 16 + (lane & 15);
#pragma unroll
      for (int rg = 0; rg < 4; ++rg) {
        int rr = wrow + fi * 16 + (lane >> 4) * 4 + rg;
        float v = acc[fi][fj][rg] + bsh[rr];
        P[(size_t)rr * MPAD + p] = f2bf(v);
      }
    }
}

// ---------------- unpack: gather packed bf16 result -> f32 output ------------
__global__ __launch_bounds__(256) void k_unpack(const unsigned short* __restrict__ P,
                                                const int* __restrict__ dst,
                                                float* __restrict__ out) {
  int t = threadIdx.x;
  long p0 = (long)blockIdx.x * 256;
  int d = dst[p0 + t];
  for (int n = 0; n < 256; ++n)
    out[(size_t)n * M_PIX + p0 + t] = bf2f(P[(size_t)n * MPAD + d]);
}

// =============================================================================
extern "C" void kernel_launch(void* const* d_in, const int* in_sizes, int n_in,
                              void* d_out, int out_size, void* d_ws, size_t ws_size,
                              hipStream_t stream) {
  const float* cfeat = (const float*)d_in[0];
  const float* sfeat = (const float*)d_in[1];
  const int* seg_c   = (const int*)d_in[2];
  const int* seg_s   = (const int*)d_in[3];

  char* ws = (char*)d_ws;
  size_t o = 0;
  auto take = [&](size_t b) { size_t r = o; o += (b + 255) & ~(size_t)255; return r; };

  unsigned short* P  = (unsigned short*)(ws + take((size_t)NCH * MPAD * 2));
  size_t zero_b = o;
  float* G           = (float*)(ws + take((size_t)2 * 8 * 65536 * 4));
  float* sum         = (float*)(ws + take((size_t)2 * 8 * 256 * 4));
  int*   hist        = (int*)(ws + take((size_t)2 * 128 * 8 * 4));
  size_t zero_e = o;
  unsigned short* Tb = (unsigned short*)(ws + take((size_t)8 * 65536 * 2));
  int*   dst         = (int*)(ws + take((size_t)2 * M_PIX * 4));
  float* means       = (float*)(ws + take((size_t)2 * 8 * 256 * 4));
  float* bvec        = (float*)(ws + take((size_t)8 * 256 * 4));
  int*   base        = (int*)(ws + take((size_t)2 * 128 * 8 * 4));
  int*   off         = (int*)(ws + take((size_t)2 * 9 * 4));
  int*   cnt         = (int*)(ws + take((size_t)2 * 8 * 4));
  int*   valid       = (int*)(ws + take((size_t)8 * 4));
  (void)ws_size; (void)n_in; (void)in_sizes; (void)out_size;

  hipMemsetAsync(ws + zero_b, 0, zero_e - zero_b, stream);

  k_hist<<<dim3(128), dim3(256), 0, stream>>>(seg_c, seg_s, hist);
  k_scan<<<dim3(1), dim3(256), 0, stream>>>(hist, base, off, cnt, valid);
  k_rank<<<dim3(128), dim3(256), 0, stream>>>(seg_c, seg_s, base, dst);

  // style (side 1) first, then content (side 0); P is reused, stream-serial.
  for (int s = 1; s >= 0; --s) {
    const float* feat = s ? sfeat : cfeat;
    k_padzero<<<dim3(9), dim3(256), 0, stream>>>(P, off + s * 9, cnt + s * 8);
    k_pack<<<dim3(1024), dim3(256), 0, stream>>>(feat, dst + (size_t)s * M_PIX, P);
    k_psum<<<dim3(520, 32), dim3(256), 0, stream>>>(P, off + s * 9, sum + (size_t)s * 8 * 256);
    k_gram<<<dim3(260, 8, 3), dim3(256), 0, stream>>>(P, off + s * 9, G + (size_t)s * 8 * 65536);
  }

  k_cov<<<dim3(16), dim3(256), 0, stream>>>(G, sum, cnt, means);
  k_chol<<<dim3(16), dim3(512), 0, stream>>>(G);
  k_T<<<dim3(8), dim3(512), 0, stream>>>(G, means, valid, Tb, bvec);
  k_outgemm<<<dim3(2080), dim3(256), 0, stream>>>(P, Tb, bvec, off);
  k_unpack<<<dim3(1024), dim3(256), 0, stream>>>(P, dst, (float*)d_out);
}

// Round 4
// 1691.570 us; speedup vs baseline: 1.8746x; 1.1387x over previous
//
#include <hip/hip_runtime.h>

#define NCH   256
#define M_PIX 262144
#define MPAD  266240   // 520*512 ; >= M_PIX + 8*512 worst-case alignment pad
#define LDA   40       // padded LDS leading dim (bf16 elements) for 32-wide k tiles

typedef short bf16x8 __attribute__((ext_vector_type(8)));
typedef float f32x4  __attribute__((ext_vector_type(4)));

__device__ __forceinline__ unsigned short f2bf(float f) {
  union { float f; unsigned u; } v; v.f = f;
  unsigned r = v.u + 0x7FFFu + ((v.u >> 16) & 1u);
  return (unsigned short)(r >> 16);
}
__device__ __forceinline__ float bf2f(unsigned short h) {
  union { unsigned u; float f; } v; v.u = ((unsigned)h) << 16;
  return v.f;
}
__device__ __forceinline__ int packoff(int j) { return j * 256 - ((j * (j - 1)) >> 1); }

// ---------------- histogram: per-2048-pixel-block label counts, both segs ----
__global__ __launch_bounds__(256) void k_hist(const int* __restrict__ seg_c,
                                              const int* __restrict__ seg_s,
                                              int* __restrict__ hist) {
  __shared__ int h[16];
  int t = threadIdx.x;
  if (t < 16) h[t] = 0;
  __syncthreads();
  int p0 = blockIdx.x * 2048 + t * 8;
#pragma unroll
  for (int e = 0; e < 8; ++e) {
    atomicAdd(&h[seg_c[p0 + e] & 7], 1);
    atomicAdd(&h[8 + (seg_s[p0 + e] & 7)], 1);
  }
  __syncthreads();
  if (t < 8) hist[blockIdx.x * 8 + t] = h[t];
  else if (t < 16) hist[1024 + blockIdx.x * 8 + (t - 8)] = h[t];
}

// ---------------- scan: totals, 512-aligned offsets, per-block bases, valid --
__global__ __launch_bounds__(256) void k_scan(const int* __restrict__ hist,
                                              int* __restrict__ base,
                                              int* __restrict__ off,
                                              int* __restrict__ cnt,
                                              int* __restrict__ valid) {
  __shared__ int lh[2048];
  __shared__ int tot[16];
  __shared__ int loff[2][9];
  int t = threadIdx.x;
  for (int i = t; i < 2048; i += 256) lh[i] = hist[i];
  __syncthreads();
  if (t < 16) {
    int s = t >> 3, l = t & 7, acc = 0;
    for (int b = 0; b < 128; ++b) acc += lh[s * 1024 + b * 8 + l];
    tot[t] = acc;
  }
  __syncthreads();
  if (t < 2) {
    int run = 0;
    for (int l = 0; l < 8; ++l) {
      loff[t][l] = run;
      run = (run + tot[t * 8 + l] + 511) & ~511;
    }
    loff[t][8] = run;
    for (int l = 0; l < 9; ++l) off[t * 9 + l] = loff[t][l];
    for (int l = 0; l < 8; ++l) cnt[t * 8 + l] = tot[t * 8 + l];
  }
  __syncthreads();
  if (t < 8) {
    long nc = tot[t], ns = tot[8 + t];
    valid[t] = (nc > 10 && ns > 10 && nc < 100 * ns && ns < 100 * nc) ? 1 : 0;
  }
  if (t < 16) {
    int s = t >> 3, l = t & 7;
    int run = loff[s][l];
    for (int b = 0; b < 128; ++b) {
      base[s * 1024 + b * 8 + l] = run;
      run += lh[s * 1024 + b * 8 + l];
    }
  }
}

// ---------------- rank: stable per-pixel destination slot (counting sort) ----
__global__ __launch_bounds__(256) void k_rank(const int* __restrict__ seg_c,
                                              const int* __restrict__ seg_s,
                                              const int* __restrict__ base,
                                              int* __restrict__ dst) {
  __shared__ int sc[8 * 272];
  __shared__ int rb[256 * 8];
  __shared__ int bb[8];
  int t = threadIdx.x;
  for (int s = 0; s < 2; ++s) {
    const int* seg = s ? seg_s : seg_c;
    const int* bas = base + s * 1024 + blockIdx.x * 8;
    int* dd = dst + (size_t)s * M_PIX;
    int p0 = blockIdx.x * 2048 + t * 8;
    unsigned pk2 = 0, cpk = 0;
#pragma unroll
    for (int e = 0; e < 8; ++e) {
      int lb = seg[p0 + e] & 7;
      pk2 |= (unsigned)lb << (3 * e);
      cpk += 1u << (4 * lb);
    }
#pragma unroll
    for (int lq = 0; lq < 8; ++lq) sc[lq * 272 + t] = (int)((cpk >> (4 * lq)) & 15u);
    if (t < 8) bb[t] = bas[t];
    __syncthreads();
    for (int d = 1; d < 256; d <<= 1) {
      int v[8];
#pragma unroll
      for (int lq = 0; lq < 8; ++lq)
        v[lq] = sc[lq * 272 + t] + ((t >= d) ? sc[lq * 272 + t - d] : 0);
      __syncthreads();
#pragma unroll
      for (int lq = 0; lq < 8; ++lq) sc[lq * 272 + t] = v[lq];
      __syncthreads();
    }
#pragma unroll
    for (int lq = 0; lq < 8; ++lq)
      rb[t * 8 + lq] = bb[lq] + sc[lq * 272 + t] - (int)((cpk >> (4 * lq)) & 15u);
#pragma unroll
    for (int e = 0; e < 8; ++e) {
      int lb = (int)((pk2 >> (3 * e)) & 7u);
      int dpos = rb[t * 8 + lb]++;
      dd[p0 + e] = dpos;
    }
    __syncthreads();
  }
}

// ---------------- zero the alignment pads of P -------------------------------
__global__ __launch_bounds__(256) void k_padzero(unsigned short* __restrict__ P,
                                                 const int* __restrict__ off,
                                                 const int* __restrict__ cnt) {
  int l = blockIdx.x;
  int c0, c1;
  if (l < 8) { c0 = off[l] + cnt[l]; c1 = off[l + 1]; }
  else       { c0 = off[8];          c1 = MPAD; }
  int w = c1 - c0;
  if (w <= 0) return;
  for (int r = 0; r < 256; ++r)
    for (int cc = threadIdx.x; cc < w; cc += 256)
      P[(size_t)r * MPAD + c0 + cc] = 0;
}

// ---------------- pack: scatter f32 -> packed bf16 (stable order) ------------
__global__ __launch_bounds__(256) void k_pack(const float* __restrict__ feat,
                                              const int* __restrict__ dst,
                                              unsigned short* __restrict__ P) {
  int t = threadIdx.x;
  long p0 = (long)blockIdx.x * 256;
  int d = dst[p0 + t];
  for (int n = 0; n < 256; ++n) {
    float v = feat[(size_t)n * M_PIX + p0 + t];
    P[(size_t)n * MPAD + d] = f2bf(v);
  }
}

// ---------------- per-(label,channel) sums over packed data ------------------
__global__ __launch_bounds__(256) void k_psum(const unsigned short* __restrict__ P,
                                              const int* __restrict__ off,
                                              float* __restrict__ sum) {
  long p0 = (long)blockIdx.x * 512;
  if (p0 >= off[8]) return;
  int l = 0;
  while (l < 7 && p0 >= off[l + 1]) ++l;
  int t = threadIdx.x;
  __shared__ float wsum[4];
#pragma unroll 1
  for (int e = 0; e < 8; ++e) {
    int n = blockIdx.y * 8 + e;
    unsigned v = *(const unsigned*)&P[(size_t)n * MPAD + p0 + 2 * t];
    float f = bf2f((unsigned short)(v & 0xFFFFu)) + bf2f((unsigned short)(v >> 16));
#pragma unroll
    for (int d = 32; d > 0; d >>= 1) f += __shfl_down(f, d, 64);
    if ((t & 63) == 0) wsum[t >> 6] = f;
    __syncthreads();
    if (t == 0) atomicAdd(&sum[l * 256 + n], wsum[0] + wsum[1] + wsum[2] + wsum[3]);
    __syncthreads();
  }
}

// ---------------- Gram: G_l += P_l P_l^T  (bf16 MFMA, lower quadrants) -------
__global__ __launch_bounds__(256) void k_gram(const unsigned short* __restrict__ P,
                                              const int* __restrict__ off,
                                              float* __restrict__ G) {
  int l = blockIdx.y;
  long o0 = off[l], o1 = off[l + 1];
  long k0 = o0 + (long)blockIdx.x * 1024;
  if (k0 >= o1) return;
  long rem = o1 - k0;
  int ks = rem > 1024 ? 1024 : (int)rem;     // always a multiple of 512
  int qi = (blockIdx.z == 0) ? 0 : 1;
  int qj = (blockIdx.z == 2) ? 1 : 0;

  __shared__ unsigned short As[128 * LDA];
  __shared__ unsigned short Bs[128 * LDA];

  int t = threadIdx.x;
  int wave = t >> 6, lane = t & 63;
  int wr = (wave >> 1) * 64, wc = (wave & 1) * 64;

  f32x4 acc[4][4] = {};

  for (int kk = 0; kk < ks; kk += 32) {
#pragma unroll
    for (int it = 0; it < 2; ++it) {
      int slot = t + it * 256;
      int rr = slot >> 2, gg = slot & 3;
      *(uint4*)&As[rr * LDA + gg * 8] =
          *(const uint4*)&P[(size_t)(qi * 128 + rr) * MPAD + (size_t)(k0 + kk) + gg * 8];
      *(uint4*)&Bs[rr * LDA + gg * 8] =
          *(const uint4*)&P[(size_t)(qj * 128 + rr) * MPAD + (size_t)(k0 + kk) + gg * 8];
    }
    __syncthreads();
    bf16x8 bfr[4];
#pragma unroll
    for (int fj = 0; fj < 4; ++fj)
      bfr[fj] = *(const bf16x8*)&Bs[(wc + fj * 16 + (lane & 15)) * LDA + (lane >> 4) * 8];
#pragma unroll
    for (int fi = 0; fi < 4; ++fi) {
      bf16x8 afr = *(const bf16x8*)&As[(wr + fi * 16 + (lane & 15)) * LDA + (lane >> 4) * 8];
#pragma unroll
      for (int fj = 0; fj < 4; ++fj)
        acc[fi][fj] = __builtin_amdgcn_mfma_f32_16x16x32_bf16(afr, bfr[fj], acc[fi][fj], 0, 0, 0);
    }
    __syncthreads();
  }
  float* Gl = G + ((size_t)l << 16);
  int rb = qi * 128 + wr, cb = qj * 128 + wc;
#pragma unroll
  for (int fi = 0; fi < 4; ++fi)
#pragma unroll
    for (int fj = 0; fj < 4; ++fj) {
      int cc = cb + fj * 16 + (lane & 15);
#pragma unroll
      for (int rg = 0; rg < 4; ++rg) {
        int rr = rb + fi * 16 + (lane >> 4) * 4 + rg;
        atomicAdd(&Gl[rr * 256 + cc], acc[fi][fj][rg]);
      }
    }
}

// ---------------- cov = (G - n*mu*mu^T)/(n-1), lower triangle in place -------
__global__ __launch_bounds__(256) void k_cov(float* __restrict__ G,
                                             const float* __restrict__ sum,
                                             const int* __restrict__ cnt,
                                             float* __restrict__ means) {
  int bid = blockIdx.x;                       // side*8 + l
  float* A = G + ((size_t)bid << 16);
  int t = threadIdx.x;
  __shared__ float mu[256];
  float fc = (float)cnt[bid];
  float m = sum[bid * 256 + t] / fmaxf(fc, 1.0f);
  mu[t] = m;
  means[bid * 256 + t] = m;
  __syncthreads();
  float rdiv = 1.0f / fmaxf(fmaxf(fc, 1.0f) - 1.0f, 1.0f);
  float mt = mu[t];
  for (int i = t; i < 256; ++i) {             // lower triangle only
    float g = A[i * 256 + t];
    A[i * 256 + t] = (g - fc * mu[i] * mt) * rdiv;
  }
}

// ---------------- blocked Cholesky (32-col panels) ---------------------------
// Packed col-major lower triangle in LDS: element (i,j) at Lp[packoff(j)+i-j].
// Diag block factored entirely in REGISTERS by lanes 0-31 (one row per lane)
// using __shfl broadcasts -- no LDS in the dependence chain (round-3 lesson:
// LDS RMW chains serialize at ~130cy each due to alias-conservative waitcnt).
__global__ __launch_bounds__(512) void k_chol(float* __restrict__ G) {
  float* A = G + ((size_t)blockIdx.x << 16);
  __shared__ float Lp[32896];
  __shared__ float Db[32 * 33];
  __shared__ float rdg[32];
  int t = threadIdx.x;

  for (int i = 0; i < 256; ++i)
    for (int j = t; j <= i; j += 512)
      Lp[packoff(j) + (i - j)] = A[i * 256 + j];
  __syncthreads();

#pragma unroll 1
  for (int pb = 0; pb < 8; ++pb) {
    int jbase = pb * 32;
    int H2 = 256 - jbase - 32;               // trailing height

    // ---- stage diag block into Db ----
    for (int idx = t; idx < 1024; idx += 512) {
      int i = idx >> 5, j = idx & 31;
      Db[i * 33 + j] = (i >= j) ? Lp[packoff(jbase + j) + (i - j)] : 0.0f;
    }
    __syncthreads();

    // ---- lanes 0-31: factor 32x32 block in registers via shfl ----
    if (t < 32) {
      float x[32];
#pragma unroll
      for (int k = 0; k < 32; ++k) x[k] = Db[t * 33 + k];
#pragma unroll
      for (int j = 0; j < 32; ++j) {
        float dj = __shfl(x[j], j, 64);      // updated diag from lane j
        float rd = 1.0f / sqrtf(dj);
        float lj = x[j] * rd;                // lane>=j: L[lane][j]; lane j: sqrt(dj)
        x[j] = lj;
#pragma unroll
        for (int k = j + 1; k < 32; ++k) {
          float lkj = __shfl(lj, k, 64);     // L[k][j] from lane k
          x[k] -= lj * lkj;
        }
      }
#pragma unroll
      for (int k = 0; k < 32; ++k) Db[t * 33 + k] = x[k];
      rdg[t] = 1.0f / x[t];
    }
    __syncthreads();

    // ---- write factored diag block back ----
    for (int idx = t; idx < 1024; idx += 512) {
      int i = idx >> 5, j = idx & 31;
      if (i >= j) Lp[packoff(jbase + j) + (i - j)] = Db[i * 33 + j];
    }

    // ---- L21 solve: one thread per trailing row (registers, static) ----
    if (t < H2) {
      int ig = jbase + 32 + t;
      float xx[32];
#pragma unroll
      for (int j = 0; j < 32; ++j)
        xx[j] = Lp[packoff(jbase + j) + (ig - jbase - j)];
#pragma unroll
      for (int j = 0; j < 32; ++j) {
        float x = xx[j];
#pragma unroll
        for (int k = 0; k < 32; ++k)
          if (k < j) x -= xx[k] * Db[j * 33 + k];
        xx[j] = x * rdg[j];
      }
#pragma unroll
      for (int j = 0; j < 32; ++j)
        Lp[packoff(jbase + j) + (ig - jbase - j)] = xx[j];
    }
    __syncthreads();

    // ---- trailing update: 4x4 register tiles ----
    if (H2 > 0) {
      int cbp[32];
#pragma unroll
      for (int jl = 0; jl < 32; ++jl)
        cbp[jl] = packoff(jbase + jl) - (jbase + jl);
      int nts = H2 >> 2;
      int ntiles = (nts * (nts + 1)) >> 1;
#pragma unroll 1
      for (int tile = t; tile < ntiles; tile += 512) {
        int ti = (int)((sqrtf(8.0f * (float)tile + 1.0f) - 1.0f) * 0.5f);
        while (((ti * (ti + 1)) >> 1) > tile) --ti;
        while ((((ti + 1) * (ti + 2)) >> 1) <= tile) ++ti;
        int tj = tile - ((ti * (ti + 1)) >> 1);
        int i0 = jbase + 32 + ti * 4, j0 = jbase + 32 + tj * 4;
        float acc[4][4] = {};
#pragma unroll
        for (int jl = 0; jl < 32; ++jl) {
          float pi0 = Lp[cbp[jl] + i0];
          float pi1 = Lp[cbp[jl] + i0 + 1];
          float pi2 = Lp[cbp[jl] + i0 + 2];
          float pi3 = Lp[cbp[jl] + i0 + 3];
          float pj0 = Lp[cbp[jl] + j0];
          float pj1 = Lp[cbp[jl] + j0 + 1];
          float pj2 = Lp[cbp[jl] + j0 + 2];
          float pj3 = Lp[cbp[jl] + j0 + 3];
          acc[0][0] += pi0 * pj0; acc[0][1] += pi0 * pj1;
          acc[0][2] += pi0 * pj2; acc[0][3] += pi0 * pj3;
          acc[1][0] += pi1 * pj0; acc[1][1] += pi1 * pj1;
          acc[1][2] += pi1 * pj2; acc[1][3] += pi1 * pj3;
          acc[2][0] += pi2 * pj0; acc[2][1] += pi2 * pj1;
          acc[2][2] += pi2 * pj2; acc[2][3] += pi2 * pj3;
          acc[3][0] += pi3 * pj0; acc[3][1] += pi3 * pj1;
          acc[3][2] += pi3 * pj2; acc[3][3] += pi3 * pj3;
        }
#pragma unroll
        for (int c = 0; c < 4; ++c) {
          int jg = j0 + c;
          int colb = packoff(jg) - jg;
#pragma unroll
          for (int r = 0; r < 4; ++r) {
            int ig2 = i0 + r;
            if (ig2 >= jg) Lp[colb + ig2] -= acc[r][c];
          }
        }
      }
    }
    __syncthreads();
  }

  for (int j = 0; j < 256; ++j) {             // write L column-major: A[j*256+i] = L[i][j]
    int n2 = 256 - j, bse = packoff(j);
    for (int e = t; e < n2; e += 512) A[j * 256 + j + e] = Lp[bse + e];
  }
}

// ---------------- T = Ls * Lc^{-1}: blocked right-looking solve --------------
// Panel solve now runs ENTIRELY in the owner half's registers (rq is already
// there); LDS only for wave-uniform broadcasts. 3 barriers/panel (was 34).
#define RQ_INIT(q, rq)                                                          \
  _Pragma("unroll") for (int kl = 0; kl < 32; ++kl) {                           \
    int kg = h * 128 + q * 32 + kl;                                             \
    rq[kl] = (i >= kg) ? Ls[(size_t)kg * 256 + i] : 0.0f;                       \
  }

#define SOLVE_Q(rq)                                                             \
  { float tp[32];                                                               \
    _Pragma("unroll") for (int jl = 31; jl >= 0; --jl) {                        \
      float tij = rq[jl] * rdg[jl];                                             \
      tp[jl] = tij;                                                             \
      _Pragma("unroll") for (int kl = 0; kl < 32; ++kl)                         \
        if (kl < jl) rq[kl] -= tij * LcRows[jl * 260 + jbase + kl];             \
    }                                                                           \
    _Pragma("unroll") for (int jl = 0; jl < 32; ++jl) Tp[i * 33 + jl] = tp[jl]; }

#define P2Q(q, rq)                                                              \
  if ((h * 128 + q * 32 + 32) <= jbase) {                                       \
    _Pragma("unroll") for (int kg = 0; kg < 8; ++kg) {                          \
      _Pragma("unroll") for (int jl = 0; jl < 32; ++jl) {                       \
        const float4 lc =                                                       \
            *(const float4*)&LcRows[jl * 260 + h * 128 + q * 32 + kg * 4];      \
        rq[kg * 4 + 0] -= tv[jl] * lc.x;                                        \
        rq[kg * 4 + 1] -= tv[jl] * lc.y;                                        \
        rq[kg * 4 + 2] -= tv[jl] * lc.z;                                        \
        rq[kg * 4 + 3] -= tv[jl] * lc.w;                                        \
      }                                                                         \
    }                                                                           \
  }

__global__ __launch_bounds__(512) void k_T(const float* __restrict__ G,
                                           const float* __restrict__ means,
                                           const int* __restrict__ valid,
                                           unsigned short* __restrict__ Tb,
                                           float* __restrict__ bvec) {
  int l = blockIdx.x;
  int t = threadIdx.x;
  unsigned short* Tbl = Tb + ((size_t)l << 16);
  if (!valid[l]) {
    for (int x = t; x < 65536; x += 512) {
      int rr = x >> 8, cc = x & 255;
      Tbl[x] = f2bf(rr == cc ? 1.0f : 0.0f);
    }
    if (t < 256) bvec[l * 256 + t] = 0.0f;
    return;
  }
  const float* Lc = G + ((size_t)l << 16);        // content L, col-major lower
  const float* Ls = G + ((size_t)(8 + l) << 16);  // style L, col-major lower

  __shared__ float Tp[256 * 33];
  __shared__ float LcRows[32 * 260];
  __shared__ float rdg[32];
  __shared__ float muc[256];

  int i = t & 255, h = t >> 8;

  if (t < 256) muc[t] = means[l * 256 + t];

  float r0[32], r1[32], r2[32], r3[32];
  RQ_INIT(0, r0) RQ_INIT(1, r1) RQ_INIT(2, r2) RQ_INIT(3, r3)
  float bacc = 0.0f;

#pragma unroll 1
  for (int jb = 7; jb >= 0; --jb) {
    int jbase = jb * 32;
    __syncthreads();                              // protect LDS from prev readers
    for (int idx = t; idx < 32 * 256; idx += 512) {
      int c = idx >> 5, jl = idx & 31;
      int j = jbase + jl;
      LcRows[jl * 260 + c] = (c <= j) ? Lc[(size_t)c * 256 + j] : 0.0f;
    }
    if (t < 32) rdg[t] = 1.0f / Lc[(size_t)(jbase + t) * 256 + (jbase + t)];
    __syncthreads();

    // panel solve in owner half's registers
    if (h == (jb >> 2)) {
      int q = jb & 3;
      if (q == 0) { SOLVE_Q(r0) }
      else if (q == 1) { SOLVE_Q(r1) }
      else if (q == 2) { SOLVE_Q(r2) }
      else { SOLVE_Q(r3) }
    }
    __syncthreads();

#pragma unroll
    for (int e = 0; e < 16; ++e) {
      int jl = h * 16 + e;
      Tbl[(size_t)i * 256 + jbase + jl] = f2bf(Tp[i * 33 + jl]);
    }
    if (h == 0) {
#pragma unroll
      for (int jl = 0; jl < 32; ++jl) bacc += Tp[i * 33 + jl] * muc[jbase + jl];
    }

    // trailing register update  r -= Tpanel * LcRows
    float tv[32];
#pragma unroll
    for (int jl = 0; jl < 32; ++jl) tv[jl] = Tp[i * 33 + jl];
    P2Q(0, r0) P2Q(1, r1) P2Q(2, r2) P2Q(3, r3)
  }

  if (h == 0) bvec[l * 256 + i] = means[(8 + l) * 256 + i] - bacc;
}

// ---------------- out = T_l * x + b_l on packed pixels (in place in P) -------
__global__ __launch_bounds__(256) void k_outgemm(unsigned short* __restrict__ P,
                                                 const unsigned short* __restrict__ Tb,
                                                 const float* __restrict__ bvec,
                                                 const int* __restrict__ off) {
  long px0 = (long)blockIdx.x * 128;
  if (px0 >= off[8]) return;
  int l = 0;
  while (l < 7 && px0 >= off[l + 1]) ++l;
  const unsigned short* Tl = Tb + ((size_t)l << 16);

  __shared__ unsigned short As[256 * LDA];
  __shared__ unsigned short Bs[128 * LDA];
  __shared__ float bsh[256];

  int t = threadIdx.x, wave = t >> 6, lane = t & 63;
  int wrow = wave * 64;
  bsh[t] = bvec[l * 256 + t];

  f32x4 acc[4][8] = {};

  for (int kk = 0; kk < 256; kk += 32) {
#pragma unroll
    for (int it = 0; it < 4; ++it) {            // A: 256 rows x 32 k
      int slot = t + it * 256;
      int rr = slot >> 2, gg = slot & 3;
      *(uint4*)&As[rr * LDA + gg * 8] = *(const uint4*)&Tl[rr * 256 + kk + gg * 8];
    }
#pragma unroll
    for (int it = 0; it < 2; ++it) {            // B: transpose-stage 32k x 128px
      int slot = t + it * 256;
      int pg = slot & 15, kr = slot >> 4;
      uint4 v = *(const uint4*)&P[(size_t)(kk + kr) * MPAD + px0 + pg * 8];
      const unsigned short* vs = (const unsigned short*)&v;
      int krs = kr ^ ((pg & 3) << 3);           // k-block XOR swizzle (bank spread)
#pragma unroll
      for (int e = 0; e < 8; ++e) Bs[(pg * 8 + e) * LDA + krs] = vs[e];
    }
    __syncthreads();
    if (kk < wrow + 64) {                       // T is lower-triangular: skip dead k-tiles
      bf16x8 bfr[8];
#pragma unroll
      for (int fj = 0; fj < 8; ++fj) {
        int px = fj * 16 + (lane & 15);
        int gs = (lane >> 4) ^ ((px >> 3) & 3);
        bfr[fj] = *(const bf16x8*)&Bs[px * LDA + gs * 8];
      }
#pragma unroll
      for (int fi = 0; fi < 4; ++fi) {
        if (wrow + fi * 16 + 15 >= kk) {
          bf16x8 afr = *(const bf16x8*)&As[(wrow + fi * 16 + (lane & 15)) * LDA + (lane >> 4) * 8];
#pragma unroll
          for (int fj = 0; fj < 8; ++fj)
            acc[fi][fj] = __builtin_amdgcn_mfma_f32_16x16x32_bf16(afr, bfr[fj], acc[fi][fj], 0, 0, 0);
        }
      }
    }
    __syncthreads();
  }
#pragma unroll
  for (int fi = 0; fi < 4; ++fi)
#pragma unroll
    for (int fj = 0; fj < 8; ++fj) {
      long p = px0 + fj * 16 + (lane & 15);
#pragma unroll
      for (int rg = 0; rg < 4; ++rg) {
        int rr = wrow + fi * 16 + (lane >> 4) * 4 + rg;
        float v = acc[fi][fj][rg] + bsh[rr];
        P[(size_t)rr * MPAD + p] = f2bf(v);
      }
    }
}

// ---------------- unpack: gather packed bf16 result -> f32 output ------------
__global__ __launch_bounds__(256) void k_unpack(const unsigned short* __restrict__ P,
                                                const int* __restrict__ dst,
                                                float* __restrict__ out) {
  int t = threadIdx.x;
  long p0 = (long)blockIdx.x * 256;
  int d = dst[p0 + t];
  for (int n = 0; n < 256; ++n)
    out[(size_t)n * M_PIX + p0 + t] = bf2f(P[(size_t)n * MPAD + d]);
}

// =============================================================================
extern "C" void kernel_launch(void* const* d_in, const int* in_sizes, int n_in,
                              void* d_out, int out_size, void* d_ws, size_t ws_size,
                              hipStream_t stream) {
  const float* cfeat = (const float*)d_in[0];
  const float* sfeat = (const float*)d_in[1];
  const int* seg_c   = (const int*)d_in[2];
  const int* seg_s   = (const int*)d_in[3];

  char* ws = (char*)d_ws;
  size_t o = 0;
  auto take = [&](size_t b) { size_t r = o; o += (b + 255) & ~(size_t)255; return r; };

  unsigned short* P  = (unsigned short*)(ws + take((size_t)NCH * MPAD * 2));
  size_t zero_b = o;
  float* G           = (float*)(ws + take((size_t)2 * 8 * 65536 * 4));
  float* sum         = (float*)(ws + take((size_t)2 * 8 * 256 * 4));
  int*   hist        = (int*)(ws + take((size_t)2 * 128 * 8 * 4));
  size_t zero_e = o;
  unsigned short* Tb = (unsigned short*)(ws + take((size_t)8 * 65536 * 2));
  int*   dst         = (int*)(ws + take((size_t)2 * M_PIX * 4));
  float* means       = (float*)(ws + take((size_t)2 * 8 * 256 * 4));
  float* bvec        = (float*)(ws + take((size_t)8 * 256 * 4));
  int*   base        = (int*)(ws + take((size_t)2 * 128 * 8 * 4));
  int*   off         = (int*)(ws + take((size_t)2 * 9 * 4));
  int*   cnt         = (int*)(ws + take((size_t)2 * 8 * 4));
  int*   valid       = (int*)(ws + take((size_t)8 * 4));
  (void)ws_size; (void)n_in; (void)in_sizes; (void)out_size;

  hipMemsetAsync(ws + zero_b, 0, zero_e - zero_b, stream);

  k_hist<<<dim3(128), dim3(256), 0, stream>>>(seg_c, seg_s, hist);
  k_scan<<<dim3(1), dim3(256), 0, stream>>>(hist, base, off, cnt, valid);
  k_rank<<<dim3(128), dim3(256), 0, stream>>>(seg_c, seg_s, base, dst);

  // style (side 1) first, then content (side 0); P is reused, stream-serial.
  for (int s = 1; s >= 0; --s) {
    const float* feat = s ? sfeat : cfeat;
    k_padzero<<<dim3(9), dim3(256), 0, stream>>>(P, off + s * 9, cnt + s * 8);
    k_pack<<<dim3(1024), dim3(256), 0, stream>>>(feat, dst + (size_t)s * M_PIX, P);
    k_psum<<<dim3(520, 32), dim3(256), 0, stream>>>(P, off + s * 9, sum + (size_t)s * 8 * 256);
    k_gram<<<dim3(260, 8, 3), dim3(256), 0, stream>>>(P, off + s * 9, G + (size_t)s * 8 * 65536);
  }

  k_cov<<<dim3(16), dim3(256), 0, stream>>>(G, sum, cnt, means);
  k_chol<<<dim3(16), dim3(512), 0, stream>>>(G);
  k_T<<<dim3(8), dim3(512), 0, stream>>>(G, means, valid, Tb, bvec);
  k_outgemm<<<dim3(2080), dim3(256), 0, stream>>>(P, Tb, bvec, off);
  k_unpack<<<dim3(1024), dim3(256), 0, stream>>>(P, dst, (float*)d_out);
}